// Round 6
// baseline (335.276 us; speedup 1.0000x reference)
//
#include <hip/hip_runtime.h>
#include <math.h>

// ---------------------------------------------------------------------------
// u-space aggregation: out[d] = Sum_p Wp^T . ( Sum_{e->d} CGp(feat_u[src_e], Y_e) )
// Workspace (4B words):
//   cg    [0..128)                 CG tensors (alpha/norm folded)
//   cursor[128 .. +N)              zero -> hist -> prefix -> cursor -> row ends
//   zrec  [align16 .. +16E)        dst-sorted 64B records:
//            w0=src w1=P(Z0,Y0) w2=P(Z1_0,Z1_1) w3=P(Z1_2,Z3_0) w4=P(Z3_1,Z3_2)
//            w5..9 = P(Z4[0..8],0)  w10..15 = pad
//   fb    [.. +64N)                feat bf16 [N][32] uint2 {P(s,vx),P(vy,vz)}
// ---------------------------------------------------------------------------

__device__ inline float blo(unsigned u) { return __uint_as_float(u << 16); }
__device__ inline float bhi(unsigned u) { return __uint_as_float(u & 0xffff0000u); }
__device__ inline unsigned bpack(float a, float b) {
    unsigned ua = __float_as_uint(a);
    ua = (ua + 0x7fffu + ((ua >> 16) & 1u)) >> 16;
    unsigned ub = __float_as_uint(b);
    ub = (ub + 0x7fffu + ((ub >> 16) & 1u)) & 0xffff0000u;
    return ua | ub;
}

__device__ inline double dfact(int n) {
    double r = 1.0;
    for (int i = 2; i <= n; ++i) r *= (double)i;
    return r;
}

// real->complex spherical harmonic change of basis (e3nn convention)
__device__ void qmat(int l, double qr[5][5], double qi[5][5]) {
    for (int a = 0; a < 5; a++)
        for (int b = 0; b < 5; b++) { qr[a][b] = 0.0; qi[a][b] = 0.0; }
    const double inv = 0.70710678118654752440;
    for (int m = -l; m < 0; ++m) {
        qr[l + m][l - m] = inv;
        qi[l + m][l + m] = -inv;
    }
    qr[l][l] = 1.0;
    for (int m = 1; m <= l; ++m) {
        double sgn = (m & 1) ? -1.0 : 1.0;
        qr[l + m][l + m] = sgn * inv;
        qi[l + m][l - m] = sgn * inv;
    }
    if (l == 1) {          // * (-i)
        for (int a = 0; a < 5; a++)
            for (int b = 0; b < 5; b++) {
                double r = qr[a][b], im = qi[a][b];
                qr[a][b] = im; qi[a][b] = -r;
            }
    } else if (l == 2) {   // * (-1)
        for (int a = 0; a < 5; a++)
            for (int b = 0; b < 5; b++) { qr[a][b] = -qr[a][b]; qi[a][b] = -qi[a][b]; }
    }
}

// SU(2) "CG" element via the reference's exact Racah-form (all six m-dependent
// factorials in the NUMERATOR — non-standard but matches the reference).
__device__ double su2_cg_elem(int l1, int l2, int l3, int i, int k, int n) {
    int m1 = i - l1, m2 = k - l2, m3 = n - l3;
    if (m1 + m2 != m3) return 0.0;
    int vmin = -l1 + l2 + m3;
    if (-l1 + m1 > vmin) vmin = -l1 + m1;
    if (0 > vmin) vmin = 0;
    int vmax = l2 + l3 + m1;
    if (l3 - l1 + l2 < vmax) vmax = l3 - l1 + l2;
    if (l3 + m3 < vmax) vmax = l3 + m3;
    if (vmax < vmin) return 0.0;
    double c = sqrt((double)(2 * l3 + 1) * dfact(l3 + l1 - l2) *
                    dfact(l3 - l1 + l2) * dfact(l1 + l2 - l3) /
                    dfact(l1 + l2 + l3 + 1));
    c *= sqrt(dfact(l3 + m3) * dfact(l3 - m3) * dfact(l1 - m1) *
              dfact(l1 + m1) * dfact(l2 - m2) * dfact(l2 + m2));
    double s = 0.0;
    for (int v = vmin; v <= vmax; ++v) {
        double term = dfact(l2 + l3 + m1 - v) * dfact(l1 - m1 + v) /
                      (dfact(v) * dfact(l3 - l1 + l2 - v) *
                       dfact(l3 + m3 - v) * dfact(v + l1 - l2 - m3));
        if ((v + l2 + m2) & 1) term = -term;
        s += term;
    }
    return c * s;
}

// cg compute by one 256-thread block (thread t -> path p=t/45, element t%45)
__device__ void cg_compute_block(float* __restrict__ cg_out) {
    const int l1s[5] = {0, 0, 1, 1, 1};
    const int l2s[5] = {0, 1, 0, 1, 2};
    const int l3s[5] = {0, 1, 1, 0, 1};
    const int offs[5] = {0, 1, 10, 19, 28};
    const double alphas[5] = {0.125, 0.10206207261596575, 0.10206207261596575,
                              0.125, 0.10206207261596575};
    __shared__ double vals[5][45];
    int t = threadIdx.x;
    int p = t / 45, idx = t % 45;
    bool active = (t < 225);
    double acc = 0.0;
    int d1 = 0, d2 = 0, d3 = 0;
    if (active) {
        int l1 = l1s[p], l2 = l2s[p], l3 = l3s[p];
        d1 = 2 * l1 + 1; d2 = 2 * l2 + 1; d3 = 2 * l3 + 1;
        if (idx < d1 * d2 * d3) {
            int j = idx / (d2 * d3);
            int rem = idx % (d2 * d3);
            int l_ = rem / d3, m = rem % d3;
            double q1r[5][5], q1i[5][5], q2r[5][5], q2i[5][5], q3r[5][5], q3i[5][5];
            qmat(l1, q1r, q1i);
            qmat(l2, q2r, q2i);
            qmat(l3, q3r, q3i);
            for (int i = 0; i < d1; ++i)
                for (int k = 0; k < d2; ++k)
                    for (int n = 0; n < d3; ++n) {
                        double C = su2_cg_elem(l1, l2, l3, i, k, n);
                        if (C == 0.0) continue;
                        double ar = q1r[i][j], ai = q1i[i][j];
                        double br = q2r[k][l_], bi = q2i[k][l_];
                        double cr = q3r[n][m], ci = q3i[n][m];
                        double abr = ar * br - ai * bi;
                        double abi = ar * bi + ai * br;
                        acc += (abr * cr + abi * ci) * C;  // Re(a*b*conj(c))
                    }
        }
        vals[p][idx] = acc;
    }
    __syncthreads();
    if (active && idx < d1 * d2 * d3) {
        double n2 = 0.0;
        for (int q = 0; q < 45; ++q) n2 += vals[p][q] * vals[p][q];
        cg_out[offs[p] + idx] = (float)(acc * alphas[p] / sqrt(n2));
    }
}

// ---------------------------------------------------------------------------
// prep: cg (block 0) + cursor zero + feat -> bf16 transcode
// ---------------------------------------------------------------------------
__global__ __launch_bounds__(256) void prep_kernel(
    const float* __restrict__ feat, int* __restrict__ cursor,
    unsigned* __restrict__ fb, float* __restrict__ cg, int N) {
    if (blockIdx.x == 0) cg_compute_block(cg);
    int t = blockIdx.x * 256 + threadIdx.x;
    if (t < N) cursor[t] = 0;
    if (t < N * 32) {
        int n = t >> 5, u = t & 31;
        const float* f = feat + (size_t)n * 128;
        float s = f[u];
        float vx = f[32 + 3 * u], vy = f[33 + 3 * u], vz = f[34 + 3 * u];
        ((uint2*)fb)[t] = make_uint2(bpack(s, vx), bpack(vy, vz));
    }
}

__global__ __launch_bounds__(256) void hist_kernel(
    const int* __restrict__ eidx, int* __restrict__ counts, int E) {
    int t = blockIdx.x * 256 + threadIdx.x;
    if (t < E) atomicAdd(&counts[eidx[E + t]], 1);
}

// single-block exclusive scan over cursor[0..N)
__global__ __launch_bounds__(1024) void scan_kernel(int* __restrict__ cursor, int N) {
    __shared__ int lds[1024];
    int tid = threadIdx.x;
    int C = (N + 1023) >> 10;
    int lo = tid * C, hi = lo + C;
    if (hi > N) hi = N;
    int sum = 0;
    for (int j = lo; j < hi; ++j) sum += cursor[j];
    lds[tid] = sum;
    __syncthreads();
    for (int off = 1; off < 1024; off <<= 1) {
        int v = 0;
        if (tid >= off) v = lds[tid - off];
        __syncthreads();
        if (tid >= off) lds[tid] += v;
        __syncthreads();
    }
    int prefix = (tid > 0) ? lds[tid - 1] : 0;
    for (int j = lo; j < hi; ++j) {
        int c = cursor[j];
        cursor[j] = prefix;
        prefix += c;
    }
}

// ---------------------------------------------------------------------------
// zscatter: per edge compute 17 lane-invariant Z values (CG (x) Y folded),
// write one 64B-aligned record at the dst-sorted position.
// ---------------------------------------------------------------------------
__global__ __launch_bounds__(256) void zscatter_kernel(
    const int* __restrict__ eidx, const float* __restrict__ sh,
    const float* __restrict__ cg, int* __restrict__ cursor,
    unsigned* __restrict__ zrec, int E) {
    int t = blockIdx.x * 256 + threadIdx.x;
    if (t >= E) return;
    int src = eidx[t];
    int dst = eidx[E + t];
    int pos = atomicAdd(&cursor[dst], 1);
    const float* Ye = sh + (size_t)t * 9;
    float Y0 = Ye[0];
    float Y1v[3] = {Ye[1], Ye[2], Ye[3]};
    float Y2v[5] = {Ye[4], Ye[5], Ye[6], Ye[7], Ye[8]};
    float Z0 = cg[0] * Y0;
    float Z1[3], Z3[3], Z4[9];
#pragma unroll
    for (int m = 0; m < 3; ++m)
        Z1[m] = fmaf(Y1v[0], cg[1 + m],
                fmaf(Y1v[1], cg[4 + m], Y1v[2] * cg[7 + m]));
#pragma unroll
    for (int i = 0; i < 3; ++i)
        Z3[i] = fmaf(Y1v[0], cg[19 + i * 3],
                fmaf(Y1v[1], cg[19 + i * 3 + 1], Y1v[2] * cg[19 + i * 3 + 2]));
#pragma unroll
    for (int i = 0; i < 3; ++i)
#pragma unroll
        for (int m = 0; m < 3; ++m) {
            float acc = 0.f;
#pragma unroll
            for (int j = 0; j < 5; ++j)
                acc = fmaf(Y2v[j], cg[28 + (i * 5 + j) * 3 + m], acc);
            Z4[i * 3 + m] = acc;
        }
    uint4* rec = (uint4*)(zrec + (size_t)pos * 16);
    rec[0] = make_uint4((unsigned)src, bpack(Z0, Y0),
                        bpack(Z1[0], Z1[1]), bpack(Z1[2], Z3[0]));
    rec[1] = make_uint4(bpack(Z3[1], Z3[2]), bpack(Z4[0], Z4[1]),
                        bpack(Z4[2], Z4[3]), bpack(Z4[4], Z4[5]));
    rec[2] = make_uint4(bpack(Z4[6], Z4[7]), bpack(Z4[8], 0.f), 0u, 0u);
    rec[3] = make_uint4(0u, 0u, 0u, 0u);  // fill full 64B line (no RMW)
}
// After zscatter: cursor[d] == end of d's range.

// ---------------------------------------------------------------------------
// Gather (u-space): one wave per dst; lane owns u = lane&31; halves take
// alternate edges. 19 FMA/edge/lane into 11 u-space accumulators. Epilogue:
// shfl combine, c2 rotation, LDS transpose, 5-path W^T matvec, clean writes.
// ---------------------------------------------------------------------------
__global__ __launch_bounds__(256) void gather_kernel(
    const unsigned* __restrict__ fb, const unsigned* __restrict__ zrec,
    const int* __restrict__ cursor, const float* __restrict__ W,
    const float* __restrict__ cg, float* __restrict__ out, int N) {
    __shared__ float lds[4][32][13];
    int wave = (blockIdx.x * 256 + threadIdx.x) >> 6;
    int lane = threadIdx.x & 63;
    int wv = threadIdx.x >> 6;
    if (wave >= N) return;
    int start = wave ? cursor[wave - 1] : 0;
    int end = cursor[wave];
    int half = lane >> 5, u = lane & 31;

    float g0 = 0.f, g3 = 0.f;
    float g1x = 0.f, g1y = 0.f, g1z = 0.f;
    float g2x = 0.f, g2y = 0.f, g2z = 0.f;
    float g4x = 0.f, g4y = 0.f, g4z = 0.f;

    for (int idx = start + half; idx < end; idx += 2) {
        const uint4* r = (const uint4*)(zrec + (size_t)idx * 16);
        uint4 q0 = r[0], q1 = r[1];
        uint2 q2 = *(const uint2*)(zrec + (size_t)idx * 16 + 8);
        int src = (int)q0.x;
        uint2 f2 = ((const uint2*)fb)[(size_t)src * 32 + u];
        float s = blo(f2.x), vx = bhi(f2.x);
        float vy = blo(f2.y), vz = bhi(f2.y);
        float z0 = blo(q0.y), y0 = bhi(q0.y);
        float z10 = blo(q0.z), z11 = bhi(q0.z), z12 = blo(q0.w), z30 = bhi(q0.w);
        float z31 = blo(q1.x), z32 = bhi(q1.x);
        float z40 = blo(q1.y), z41 = bhi(q1.y), z42 = blo(q1.z), z43 = bhi(q1.z);
        float z44 = blo(q1.w), z45 = bhi(q1.w);
        float z46 = blo(q2.x), z47 = bhi(q2.x), z48 = blo(q2.y);

        g0 = fmaf(z0, s, g0);
        g1x = fmaf(z10, s, g1x); g1y = fmaf(z11, s, g1y); g1z = fmaf(z12, s, g1z);
        g2x = fmaf(y0, vx, g2x); g2y = fmaf(y0, vy, g2y); g2z = fmaf(y0, vz, g2z);
        g3 = fmaf(z30, vx, fmaf(z31, vy, fmaf(z32, vz, g3)));
        g4x = fmaf(vx, z40, fmaf(vy, z43, fmaf(vz, z46, g4x)));
        g4y = fmaf(vx, z41, fmaf(vy, z44, fmaf(vz, z47, g4y)));
        g4z = fmaf(vx, z42, fmaf(vy, z45, fmaf(vz, z48, g4z)));
    }
    // combine half-waves
    g0 += __shfl_xor(g0, 32);  g3 += __shfl_xor(g3, 32);
    g1x += __shfl_xor(g1x, 32); g1y += __shfl_xor(g1y, 32); g1z += __shfl_xor(g1z, 32);
    g2x += __shfl_xor(g2x, 32); g2y += __shfl_xor(g2y, 32); g2z += __shfl_xor(g2z, 32);
    g4x += __shfl_xor(g4x, 32); g4y += __shfl_xor(g4y, 32); g4z += __shfl_xor(g4z, 32);

    // rotate g2 through c2 (P2's CG applied at dst level)
    float g2cx = fmaf(g2x, cg[10], fmaf(g2y, cg[13], g2z * cg[16]));
    float g2cy = fmaf(g2x, cg[11], fmaf(g2y, cg[14], g2z * cg[17]));
    float g2cz = fmaf(g2x, cg[12], fmaf(g2y, cg[15], g2z * cg[18]));

    if (half == 0) {
        float* L = lds[wv][u];
        L[0] = g0;  L[1] = g3;
        L[2] = g1x; L[3] = g1y; L[4] = g1z;
        L[5] = g2cx; L[6] = g2cy; L[7] = g2cz;
        L[8] = g4x; L[9] = g4y; L[10] = g4z;
    }
    // same-wave LDS write->read: hardware per-wave ordering + compiler lgkmcnt

    int w = u;
    float oA = 0.f, oB = 0.f;  // half0: oA=out1[m=0], oB=out0 ; half1: oA=out1[1], oB=out1[2]
    int qm = half;             // m for oA
#pragma unroll 4
    for (int uu = 0; uu < 32; ++uu) {
        const float* L = lds[wv][uu];
        float w0 = W[uu * 32 + w];
        float w1 = W[1024 + uu * 32 + w];
        float w2 = W[2048 + uu * 32 + w];
        float w3 = W[3072 + uu * 32 + w];
        float w4 = W[4096 + uu * 32 + w];
        float G1 = L[2 + qm], G2 = L[5 + qm], G4 = L[8 + qm];
        oA = fmaf(G1, w1, fmaf(G2, w2, fmaf(G4, w4, oA)));
        float B1 = half ? L[4] : L[0];
        float B2 = half ? L[7] : L[1];
        float B3 = L[10];
        float s1 = half ? w1 : w0;
        float s2 = half ? w2 : w3;
        float s3 = half ? w4 : 0.0f;
        oB = fmaf(B1, s1, fmaf(B2, s2, fmaf(B3, s3, oB)));
    }
    float* ob = out + (size_t)wave * 128;
    if (half == 0) {
        ob[w] = oB;
        ob[32 + w * 3 + 0] = oA;
    } else {
        ob[32 + w * 3 + 1] = oA;
        ob[32 + w * 3 + 2] = oB;
    }
}

extern "C" void kernel_launch(void* const* d_in, const int* in_sizes, int n_in,
                              void* d_out, int out_size, void* d_ws, size_t ws_size,
                              hipStream_t stream) {
    const float* feat = (const float*)d_in[0];
    const float* sh = (const float*)d_in[1];
    const int* eidx = (const int*)d_in[2];
    const float* W = (const float*)d_in[3];
    float* out = (float*)d_out;
    int N = in_sizes[0] / 128;
    int E = in_sizes[1] / 9;

    float* wsf = (float*)d_ws;
    float* cg = wsf;                                     // 128 words
    int* cursor = (int*)(wsf + 128);                     // N words
    size_t zoff = (size_t)(128 + N + 15) & ~(size_t)15;  // 64B align
    unsigned* zrec = (unsigned*)(wsf + zoff);            // 16E words
    unsigned* fb = zrec + (size_t)16 * E;                // 64N words

    prep_kernel<<<(N * 32 + 255) / 256, 256, 0, stream>>>(feat, cursor, fb, cg, N);
    hist_kernel<<<(E + 255) / 256, 256, 0, stream>>>(eidx, cursor, E);
    scan_kernel<<<1, 1024, 0, stream>>>(cursor, N);
    zscatter_kernel<<<(E + 255) / 256, 256, 0, stream>>>(eidx, sh, cg, cursor, zrec, E);
    gather_kernel<<<(N * 64 + 255) / 256, 256, 0, stream>>>(fb, zrec, cursor, W, cg, out, N);
}

// Round 7
// 288.153 us; speedup vs baseline: 1.1635x; 1.1635x over previous
//
#include <hip/hip_runtime.h>
#include <math.h>

// ---------------------------------------------------------------------------
// u-space aggregation + MFMA epilogue.
//   gather:  G[n][t][u] = Sum_{e->n} z_t(Y_e) (x) feat_u[src_e]   (bf16, K=352)
//   epilog:  out[n][j]  = Sum_k G[n][k] * WB[j][k]   (16x16x32 bf16 MFMA)
// Workspace (4B words):
//   cg    [0..128)          CG tensors (alpha/norm folded)
//   cursor[128 .. +N)       memset0 -> hist -> prefix -> cursor -> row ends
//   zrec  [.. +10E)         dst-sorted 40B records (8B aligned):
//                           w0=src w1=P(y0,z1_0) w2=P(z1_1,z1_2) w3=P(z3_0,z3_1)
//                           w4=P(z3_2,z4_00) w5..8=P(z4_01..z4_22) w9=pad
//   fb    [.. +64N)         feat bf16 [N][32] uint2 {P(s,vx),P(vy,vz)}
//   G     [.. +176N)        ushort [N][352], k = t*32+u, t: 0=g0 1=g3 2-4=g1m
//                           5-7=g2i 8-10=g4m
//   WBT   [.. +22528)       ushort [128][352]  (W bf16, cg0/c2 folded)
// ---------------------------------------------------------------------------

typedef __attribute__((ext_vector_type(8))) short bf16x8;
typedef __attribute__((ext_vector_type(4))) float f32x4;

__device__ inline float blo(unsigned u) { return __uint_as_float(u << 16); }
__device__ inline float bhi(unsigned u) { return __uint_as_float(u & 0xffff0000u); }
__device__ inline unsigned bpack(float a, float b) {
    unsigned ua = __float_as_uint(a);
    ua = (ua + 0x7fffu + ((ua >> 16) & 1u)) >> 16;
    unsigned ub = __float_as_uint(b);
    ub = (ub + 0x7fffu + ((ub >> 16) & 1u)) & 0xffff0000u;
    return ua | ub;
}
__device__ inline unsigned short bh(float a) {
    unsigned ua = __float_as_uint(a);
    return (unsigned short)((ua + 0x7fffu + ((ua >> 16) & 1u)) >> 16);
}

__device__ inline double dfact(int n) {
    double r = 1.0;
    for (int i = 2; i <= n; ++i) r *= (double)i;
    return r;
}

// real->complex spherical harmonic change of basis (e3nn convention)
__device__ void qmat(int l, double qr[5][5], double qi[5][5]) {
    for (int a = 0; a < 5; a++)
        for (int b = 0; b < 5; b++) { qr[a][b] = 0.0; qi[a][b] = 0.0; }
    const double inv = 0.70710678118654752440;
    for (int m = -l; m < 0; ++m) {
        qr[l + m][l - m] = inv;
        qi[l + m][l + m] = -inv;
    }
    qr[l][l] = 1.0;
    for (int m = 1; m <= l; ++m) {
        double sgn = (m & 1) ? -1.0 : 1.0;
        qr[l + m][l + m] = sgn * inv;
        qi[l + m][l - m] = sgn * inv;
    }
    if (l == 1) {          // * (-i)
        for (int a = 0; a < 5; a++)
            for (int b = 0; b < 5; b++) {
                double r = qr[a][b], im = qi[a][b];
                qr[a][b] = im; qi[a][b] = -r;
            }
    } else if (l == 2) {   // * (-1)
        for (int a = 0; a < 5; a++)
            for (int b = 0; b < 5; b++) { qr[a][b] = -qr[a][b]; qi[a][b] = -qi[a][b]; }
    }
}

// SU(2) "CG" element via the reference's exact Racah-form (all six m-dependent
// factorials in the NUMERATOR — non-standard but matches the reference).
__device__ double su2_cg_elem(int l1, int l2, int l3, int i, int k, int n) {
    int m1 = i - l1, m2 = k - l2, m3 = n - l3;
    if (m1 + m2 != m3) return 0.0;
    int vmin = -l1 + l2 + m3;
    if (-l1 + m1 > vmin) vmin = -l1 + m1;
    if (0 > vmin) vmin = 0;
    int vmax = l2 + l3 + m1;
    if (l3 - l1 + l2 < vmax) vmax = l3 - l1 + l2;
    if (l3 + m3 < vmax) vmax = l3 + m3;
    if (vmax < vmin) return 0.0;
    double c = sqrt((double)(2 * l3 + 1) * dfact(l3 + l1 - l2) *
                    dfact(l3 - l1 + l2) * dfact(l1 + l2 - l3) /
                    dfact(l1 + l2 + l3 + 1));
    c *= sqrt(dfact(l3 + m3) * dfact(l3 - m3) * dfact(l1 - m1) *
              dfact(l1 + m1) * dfact(l2 - m2) * dfact(l2 + m2));
    double s = 0.0;
    for (int v = vmin; v <= vmax; ++v) {
        double term = dfact(l2 + l3 + m1 - v) * dfact(l1 - m1 + v) /
                      (dfact(v) * dfact(l3 - l1 + l2 - v) *
                       dfact(l3 + m3 - v) * dfact(v + l1 - l2 - m3));
        if ((v + l2 + m2) & 1) term = -term;
        s += term;
    }
    return c * s;
}

// cg compute by one 256-thread block (thread t -> path p=t/45, element t%45)
__device__ void cg_compute_block(float* __restrict__ cg_out) {
    const int l1s[5] = {0, 0, 1, 1, 1};
    const int l2s[5] = {0, 1, 0, 1, 2};
    const int l3s[5] = {0, 1, 1, 0, 1};
    const int offs[5] = {0, 1, 10, 19, 28};
    const double alphas[5] = {0.125, 0.10206207261596575, 0.10206207261596575,
                              0.125, 0.10206207261596575};
    __shared__ double vals[5][45];
    int t = threadIdx.x;
    int p = t / 45, idx = t % 45;
    bool active = (t < 225);
    double acc = 0.0;
    int d1 = 0, d2 = 0, d3 = 0;
    if (active) {
        int l1 = l1s[p], l2 = l2s[p], l3 = l3s[p];
        d1 = 2 * l1 + 1; d2 = 2 * l2 + 1; d3 = 2 * l3 + 1;
        if (idx < d1 * d2 * d3) {
            int j = idx / (d2 * d3);
            int rem = idx % (d2 * d3);
            int l_ = rem / d3, m = rem % d3;
            double q1r[5][5], q1i[5][5], q2r[5][5], q2i[5][5], q3r[5][5], q3i[5][5];
            qmat(l1, q1r, q1i);
            qmat(l2, q2r, q2i);
            qmat(l3, q3r, q3i);
            for (int i = 0; i < d1; ++i)
                for (int k = 0; k < d2; ++k)
                    for (int n = 0; n < d3; ++n) {
                        double C = su2_cg_elem(l1, l2, l3, i, k, n);
                        if (C == 0.0) continue;
                        double ar = q1r[i][j], ai = q1i[i][j];
                        double br = q2r[k][l_], bi = q2i[k][l_];
                        double cr = q3r[n][m], ci = q3i[n][m];
                        double abr = ar * br - ai * bi;
                        double abi = ar * bi + ai * br;
                        acc += (abr * cr + abi * ci) * C;  // Re(a*b*conj(c))
                    }
        }
        vals[p][idx] = acc;
    }
    __syncthreads();
    if (active && idx < d1 * d2 * d3) {
        double n2 = 0.0;
        for (int q = 0; q < 45; ++q) n2 += vals[p][q] * vals[p][q];
        cg_out[offs[p] + idx] = (float)(acc * alphas[p] / sqrt(n2));
    }
}

// ---------------------------------------------------------------------------
// prep: cg (block 0) + feat->bf16 transcode + dst histogram (cursor memset
// beforehand on stream).
// ---------------------------------------------------------------------------
__global__ __launch_bounds__(256) void prep_kernel(
    const float* __restrict__ feat, const int* __restrict__ eidx,
    int* __restrict__ cursor, unsigned* __restrict__ fb,
    float* __restrict__ cg, int N, int E) {
    if (blockIdx.x == 0) cg_compute_block(cg);
    int t = blockIdx.x * 256 + threadIdx.x;
    if (t < N * 32) {
        int n = t >> 5, u = t & 31;
        const float* f = feat + (size_t)n * 128;
        float s = f[u];
        float vx = f[32 + 3 * u], vy = f[33 + 3 * u], vz = f[34 + 3 * u];
        ((uint2*)fb)[t] = make_uint2(bpack(s, vx), bpack(vy, vz));
    }
    if (t < E) atomicAdd(&cursor[eidx[E + t]], 1);
}

// ---------------------------------------------------------------------------
// scan (single block) + WBT build (needs cg from prep)
// WBT[j][k], k = t*32+u:  j<32 (out0): t0 -> cg0*w0, t1 -> w3
//   j>=32: w=(j-32)/3, m=(j-32)%3:  t2+mm -> (mm==m)*w1 ;
//   t5+i -> c2[i][m]*w2 ; t8+mm -> (mm==m)*w4
// ---------------------------------------------------------------------------
__global__ __launch_bounds__(1024) void scan_wbt_kernel(
    int* __restrict__ cursor, const float* __restrict__ W,
    const float* __restrict__ cg, unsigned short* __restrict__ WBT, int N) {
    __shared__ int lds[1024];
    int tid = threadIdx.x;
    int C = (N + 1023) >> 10;
    int lo = tid * C, hi = lo + C;
    if (hi > N) hi = N;
    int sum = 0;
    for (int j = lo; j < hi; ++j) sum += cursor[j];
    lds[tid] = sum;
    __syncthreads();
    for (int off = 1; off < 1024; off <<= 1) {
        int v = 0;
        if (tid >= off) v = lds[tid - off];
        __syncthreads();
        if (tid >= off) lds[tid] += v;
        __syncthreads();
    }
    int prefix = (tid > 0) ? lds[tid - 1] : 0;
    for (int j = lo; j < hi; ++j) {
        int c = cursor[j];
        cursor[j] = prefix;
        prefix += c;
    }
    // WBT build
    for (int idx = tid; idx < 128 * 352; idx += 1024) {
        int j = idx / 352, k = idx % 352;
        int t = k >> 5, u = k & 31;
        float val = 0.f;
        if (j < 32) {
            if (t == 0) val = cg[0] * W[u * 32 + j];
            else if (t == 1) val = W[3072 + u * 32 + j];
        } else {
            int w = (j - 32) / 3, m = (j - 32) % 3;
            if (t >= 2 && t <= 4) { if (t - 2 == m) val = W[1024 + u * 32 + w]; }
            else if (t >= 5 && t <= 7) { val = cg[10 + (t - 5) * 3 + m] * W[2048 + u * 32 + w]; }
            else if (t >= 8) { if (t - 8 == m) val = W[4096 + u * 32 + w]; }
        }
        WBT[idx] = bh(val);
    }
}

// ---------------------------------------------------------------------------
// zscatter: per edge compute 16 lane-invariant values (CG (x) Y folded),
// write one 40B (8B-aligned) record at the dst-sorted position.
// ---------------------------------------------------------------------------
__global__ __launch_bounds__(256) void zscatter_kernel(
    const int* __restrict__ eidx, const float* __restrict__ sh,
    const float* __restrict__ cg, int* __restrict__ cursor,
    unsigned* __restrict__ zrec, int E) {
    int t = blockIdx.x * 256 + threadIdx.x;
    if (t >= E) return;
    int src = eidx[t];
    int dst = eidx[E + t];
    int pos = atomicAdd(&cursor[dst], 1);
    const float* Ye = sh + (size_t)t * 9;
    float Y0 = Ye[0];
    float Y1v[3] = {Ye[1], Ye[2], Ye[3]};
    float Y2v[5] = {Ye[4], Ye[5], Ye[6], Ye[7], Ye[8]};
    float Z1[3], Z3[3], Z4[9];
#pragma unroll
    for (int m = 0; m < 3; ++m)
        Z1[m] = fmaf(Y1v[0], cg[1 + m],
                fmaf(Y1v[1], cg[4 + m], Y1v[2] * cg[7 + m]));
#pragma unroll
    for (int i = 0; i < 3; ++i)
        Z3[i] = fmaf(Y1v[0], cg[19 + i * 3],
                fmaf(Y1v[1], cg[19 + i * 3 + 1], Y1v[2] * cg[19 + i * 3 + 2]));
#pragma unroll
    for (int i = 0; i < 3; ++i)
#pragma unroll
        for (int m = 0; m < 3; ++m) {
            float acc = 0.f;
#pragma unroll
            for (int j = 0; j < 5; ++j)
                acc = fmaf(Y2v[j], cg[28 + (i * 5 + j) * 3 + m], acc);
            Z4[i * 3 + m] = acc;
        }
    uint2* rec = (uint2*)(zrec + (size_t)pos * 10);
    rec[0] = make_uint2((unsigned)src, bpack(Y0, Z1[0]));
    rec[1] = make_uint2(bpack(Z1[1], Z1[2]), bpack(Z3[0], Z3[1]));
    rec[2] = make_uint2(bpack(Z3[2], Z4[0]), bpack(Z4[1], Z4[2]));
    rec[3] = make_uint2(bpack(Z4[3], Z4[4]), bpack(Z4[5], Z4[6]));
    rec[4] = make_uint2(bpack(Z4[7], Z4[8]), 0u);
}
// After zscatter: cursor[d] == end of d's range.

// ---------------------------------------------------------------------------
// Gather (u-space): one wave per dst; lane owns u = lane&31; halves take
// alternate edges. 19 FMA/edge/lane into 11 accumulators; shfl combine;
// 11 coalesced ushort stores to G[n][t][u]. No LDS, no W.
// ---------------------------------------------------------------------------
__global__ __launch_bounds__(256) void gather_kernel(
    const unsigned* __restrict__ fb, const unsigned* __restrict__ zrec,
    const int* __restrict__ cursor, unsigned short* __restrict__ G, int N) {
    int wave = (blockIdx.x * 256 + threadIdx.x) >> 6;
    int lane = threadIdx.x & 63;
    if (wave >= N) return;
    int start = wave ? cursor[wave - 1] : 0;
    int end = cursor[wave];
    int half = lane >> 5, u = lane & 31;

    float g0 = 0.f, g3 = 0.f;
    float g1x = 0.f, g1y = 0.f, g1z = 0.f;
    float g2x = 0.f, g2y = 0.f, g2z = 0.f;
    float g4x = 0.f, g4y = 0.f, g4z = 0.f;

    for (int idx = start + half; idx < end; idx += 2) {
        const uint2* r = (const uint2*)(zrec + (size_t)idx * 10);
        uint2 r0 = r[0], r1 = r[1], r2 = r[2], r3 = r[3], r4 = r[4];
        int src = (int)r0.x;
        uint2 f2 = ((const uint2*)fb)[(size_t)src * 32 + u];
        float s = blo(f2.x), vx = bhi(f2.x);
        float vy = blo(f2.y), vz = bhi(f2.y);
        float y0 = blo(r0.y), z10 = bhi(r0.y);
        float z11 = blo(r1.x), z12 = bhi(r1.x);
        float z30 = blo(r1.y), z31 = bhi(r1.y);
        float z32 = blo(r2.x), z400 = bhi(r2.x);
        float z401 = blo(r2.y), z402 = bhi(r2.y);
        float z410 = blo(r3.x), z411 = bhi(r3.x);
        float z412 = blo(r3.y), z420 = bhi(r3.y);
        float z421 = blo(r4.x), z422 = bhi(r4.x);

        g0 = fmaf(y0, s, g0);
        g1x = fmaf(z10, s, g1x); g1y = fmaf(z11, s, g1y); g1z = fmaf(z12, s, g1z);
        g2x = fmaf(y0, vx, g2x); g2y = fmaf(y0, vy, g2y); g2z = fmaf(y0, vz, g2z);
        g3 = fmaf(z30, vx, fmaf(z31, vy, fmaf(z32, vz, g3)));
        g4x = fmaf(vx, z400, fmaf(vy, z410, fmaf(vz, z420, g4x)));
        g4y = fmaf(vx, z401, fmaf(vy, z411, fmaf(vz, z421, g4y)));
        g4z = fmaf(vx, z402, fmaf(vy, z412, fmaf(vz, z422, g4z)));
    }
    g0 += __shfl_xor(g0, 32);  g3 += __shfl_xor(g3, 32);
    g1x += __shfl_xor(g1x, 32); g1y += __shfl_xor(g1y, 32); g1z += __shfl_xor(g1z, 32);
    g2x += __shfl_xor(g2x, 32); g2y += __shfl_xor(g2y, 32); g2z += __shfl_xor(g2z, 32);
    g4x += __shfl_xor(g4x, 32); g4y += __shfl_xor(g4y, 32); g4z += __shfl_xor(g4z, 32);

    if (half == 0) {
        unsigned short* Gr = G + (size_t)wave * 352 + u;
        Gr[0] = bh(g0);         // t=0
        Gr[32] = bh(g3);        // t=1
        Gr[64] = bh(g1x);  Gr[96] = bh(g1y);  Gr[128] = bh(g1z);
        Gr[160] = bh(g2x); Gr[192] = bh(g2y); Gr[224] = bh(g2z);
        Gr[256] = bh(g4x); Gr[288] = bh(g4y); Gr[320] = bh(g4z);
    }
}

// ---------------------------------------------------------------------------
// Epilogue: out[n][j] = Sum_k G[n][k]*WBT[j][k] via mfma_f32_16x16x32_bf16.
// One wave per 16-dst tile; A-frags (K=352 -> 11) held in regs across the 8
// j-tiles. A: lane holds G[n0+(l&15)][kk*32+(l>>4)*8 ..+7];
// B: WBT[jt*16+(l&15)][same k] (B[k][col], col=lane&15).
// D: lane l reg i -> out[n0+(l>>4)*4+i][jt*16+(l&15)].
// ---------------------------------------------------------------------------
__global__ __launch_bounds__(256) void epilogue_kernel(
    const unsigned short* __restrict__ G, const unsigned short* __restrict__ WBT,
    float* __restrict__ out, int N) {
    int wid = (blockIdx.x * 256 + threadIdx.x) >> 6;
    int lane = threadIdx.x & 63;
    int ntiles = N >> 4;
    if (wid >= ntiles) return;
    int n0 = wid << 4;
    int r = lane & 15, q = lane >> 4;

    bf16x8 a[11];
#pragma unroll
    for (int kk = 0; kk < 11; ++kk)
        a[kk] = *(const bf16x8*)(G + (size_t)(n0 + r) * 352 + kk * 32 + q * 8);

#pragma unroll
    for (int jt = 0; jt < 8; ++jt) {
        f32x4 acc = {0.f, 0.f, 0.f, 0.f};
#pragma unroll
        for (int kk = 0; kk < 11; ++kk) {
            bf16x8 b = *(const bf16x8*)(WBT + (size_t)(jt * 16 + r) * 352 + kk * 32 + q * 8);
            acc = __builtin_amdgcn_mfma_f32_16x16x32_bf16(a[kk], b, acc, 0, 0, 0);
        }
#pragma unroll
        for (int i = 0; i < 4; ++i)
            out[(size_t)(n0 + q * 4 + i) * 128 + jt * 16 + r] = acc[i];
    }
}

extern "C" void kernel_launch(void* const* d_in, const int* in_sizes, int n_in,
                              void* d_out, int out_size, void* d_ws, size_t ws_size,
                              hipStream_t stream) {
    const float* feat = (const float*)d_in[0];
    const float* sh = (const float*)d_in[1];
    const int* eidx = (const int*)d_in[2];
    const float* W = (const float*)d_in[3];
    float* out = (float*)d_out;
    int N = in_sizes[0] / 128;
    int E = in_sizes[1] / 9;

    float* wsf = (float*)d_ws;
    float* cg = wsf;                                       // 128 words
    int* cursor = (int*)(wsf + 128);                       // N words
    size_t off = (size_t)(128 + N + 1) & ~(size_t)1;       // 8B align
    unsigned* zrec = (unsigned*)(wsf + off);               // 10E words
    unsigned* fb = zrec + (size_t)10 * E;                  // 64N words
    unsigned short* G = (unsigned short*)(fb + (size_t)64 * N);  // 176N words
    unsigned short* WBT = G + (size_t)352 * N;             // 22528 words

    hipMemsetAsync(cursor, 0, (size_t)N * sizeof(int), stream);
    prep_kernel<<<(N * 32 + 255) / 256, 256, 0, stream>>>(feat, eidx, cursor, fb, cg, N, E);
    scan_wbt_kernel<<<1, 1024, 0, stream>>>(cursor, W, cg, WBT, N);
    zscatter_kernel<<<(E + 255) / 256, 256, 0, stream>>>(eidx, sh, cg, cursor, zrec, E);
    gather_kernel<<<(N * 64 + 255) / 256, 256, 0, stream>>>(fb, zrec, cursor, G, N);
    epilogue_kernel<<<((N >> 4) * 64 + 255) / 256, 256, 0, stream>>>(G, WBT, out, N);
}

// Round 8
// 200.087 us; speedup vs baseline: 1.6757x; 1.4401x over previous
//
#include <hip/hip_runtime.h>
#include <math.h>

// ---------------------------------------------------------------------------
// u-space aggregation + MFMA epilogue.
//   gather:  G[n][t][u] = Sum_{e->n} z_t(Y_e) (x) feat_u[src_e]   (bf16, K=352)
//   epilog:  out[n][j]  = Sum_k G[n][k] * WB[j][k]   (16x16x32 bf16 MFMA)
// Workspace (4B words):
//   cg      [0..128)        CG tensors (alpha/norm folded)
//   cursor  [128 .. +N)     memset0 -> hist -> prefix -> cursor -> row ends
//   zrec    [.. +10E)       dst-sorted 40B records (8B aligned)
//   fb      [.. +64N)       feat bf16 [N][32] uint2 {P(s,vx),P(vy,vz)}
//   G       [.. +176N)      ushort [N][352], k = t*32+u
//   WBT     [.. +22528)     ushort [128][352]  (W bf16, cg0/c2 folded)
//   tilesums[.. +256)       per-tile sums for hierarchical scan
// ---------------------------------------------------------------------------

typedef __attribute__((ext_vector_type(8))) short bf16x8;
typedef __attribute__((ext_vector_type(4))) float f32x4;

__device__ inline float blo(unsigned u) { return __uint_as_float(u << 16); }
__device__ inline float bhi(unsigned u) { return __uint_as_float(u & 0xffff0000u); }
__device__ inline unsigned bpack(float a, float b) {
    unsigned ua = __float_as_uint(a);
    ua = (ua + 0x7fffu + ((ua >> 16) & 1u)) >> 16;
    unsigned ub = __float_as_uint(b);
    ub = (ub + 0x7fffu + ((ub >> 16) & 1u)) & 0xffff0000u;
    return ua | ub;
}
__device__ inline unsigned short bh(float a) {
    unsigned ua = __float_as_uint(a);
    return (unsigned short)((ua + 0x7fffu + ((ua >> 16) & 1u)) >> 16);
}

__device__ inline double dfact(int n) {
    double r = 1.0;
    for (int i = 2; i <= n; ++i) r *= (double)i;
    return r;
}

// real->complex spherical harmonic change of basis (e3nn convention)
__device__ void qmat(int l, double qr[5][5], double qi[5][5]) {
    for (int a = 0; a < 5; a++)
        for (int b = 0; b < 5; b++) { qr[a][b] = 0.0; qi[a][b] = 0.0; }
    const double inv = 0.70710678118654752440;
    for (int m = -l; m < 0; ++m) {
        qr[l + m][l - m] = inv;
        qi[l + m][l + m] = -inv;
    }
    qr[l][l] = 1.0;
    for (int m = 1; m <= l; ++m) {
        double sgn = (m & 1) ? -1.0 : 1.0;
        qr[l + m][l + m] = sgn * inv;
        qi[l + m][l - m] = sgn * inv;
    }
    if (l == 1) {          // * (-i)
        for (int a = 0; a < 5; a++)
            for (int b = 0; b < 5; b++) {
                double r = qr[a][b], im = qi[a][b];
                qr[a][b] = im; qi[a][b] = -r;
            }
    } else if (l == 2) {   // * (-1)
        for (int a = 0; a < 5; a++)
            for (int b = 0; b < 5; b++) { qr[a][b] = -qr[a][b]; qi[a][b] = -qi[a][b]; }
    }
}

// SU(2) "CG" element via the reference's exact Racah-form (all six m-dependent
// factorials in the NUMERATOR — non-standard but matches the reference).
__device__ double su2_cg_elem(int l1, int l2, int l3, int i, int k, int n) {
    int m1 = i - l1, m2 = k - l2, m3 = n - l3;
    if (m1 + m2 != m3) return 0.0;
    int vmin = -l1 + l2 + m3;
    if (-l1 + m1 > vmin) vmin = -l1 + m1;
    if (0 > vmin) vmin = 0;
    int vmax = l2 + l3 + m1;
    if (l3 - l1 + l2 < vmax) vmax = l3 - l1 + l2;
    if (l3 + m3 < vmax) vmax = l3 + m3;
    if (vmax < vmin) return 0.0;
    double c = sqrt((double)(2 * l3 + 1) * dfact(l3 + l1 - l2) *
                    dfact(l3 - l1 + l2) * dfact(l1 + l2 - l3) /
                    dfact(l1 + l2 + l3 + 1));
    c *= sqrt(dfact(l3 + m3) * dfact(l3 - m3) * dfact(l1 - m1) *
              dfact(l1 + m1) * dfact(l2 - m2) * dfact(l2 + m2));
    double s = 0.0;
    for (int v = vmin; v <= vmax; ++v) {
        double term = dfact(l2 + l3 + m1 - v) * dfact(l1 - m1 + v) /
                      (dfact(v) * dfact(l3 - l1 + l2 - v) *
                       dfact(l3 + m3 - v) * dfact(v + l1 - l2 - m3));
        if ((v + l2 + m2) & 1) term = -term;
        s += term;
    }
    return c * s;
}

// cg compute by one 256-thread block (thread t -> path p=t/45, element t%45)
__device__ void cg_compute_block(float* __restrict__ cg_out) {
    const int l1s[5] = {0, 0, 1, 1, 1};
    const int l2s[5] = {0, 1, 0, 1, 2};
    const int l3s[5] = {0, 1, 1, 0, 1};
    const int offs[5] = {0, 1, 10, 19, 28};
    const double alphas[5] = {0.125, 0.10206207261596575, 0.10206207261596575,
                              0.125, 0.10206207261596575};
    __shared__ double vals[5][45];
    int t = threadIdx.x;
    int p = t / 45, idx = t % 45;
    bool active = (t < 225);
    double acc = 0.0;
    int d1 = 0, d2 = 0, d3 = 0;
    if (active) {
        int l1 = l1s[p], l2 = l2s[p], l3 = l3s[p];
        d1 = 2 * l1 + 1; d2 = 2 * l2 + 1; d3 = 2 * l3 + 1;
        if (idx < d1 * d2 * d3) {
            int j = idx / (d2 * d3);
            int rem = idx % (d2 * d3);
            int l_ = rem / d3, m = rem % d3;
            double q1r[5][5], q1i[5][5], q2r[5][5], q2i[5][5], q3r[5][5], q3i[5][5];
            qmat(l1, q1r, q1i);
            qmat(l2, q2r, q2i);
            qmat(l3, q3r, q3i);
            for (int i = 0; i < d1; ++i)
                for (int k = 0; k < d2; ++k)
                    for (int n = 0; n < d3; ++n) {
                        double C = su2_cg_elem(l1, l2, l3, i, k, n);
                        if (C == 0.0) continue;
                        double ar = q1r[i][j], ai = q1i[i][j];
                        double br = q2r[k][l_], bi = q2i[k][l_];
                        double cr = q3r[n][m], ci = q3i[n][m];
                        double abr = ar * br - ai * bi;
                        double abi = ar * bi + ai * br;
                        acc += (abr * cr + abi * ci) * C;  // Re(a*b*conj(c))
                    }
        }
        vals[p][idx] = acc;
    }
    __syncthreads();
    if (active && idx < d1 * d2 * d3) {
        double n2 = 0.0;
        for (int q = 0; q < 45; ++q) n2 += vals[p][q] * vals[p][q];
        cg_out[offs[p] + idx] = (float)(acc * alphas[p] / sqrt(n2));
    }
}

// ---------------------------------------------------------------------------
// prep: cg (block 0) + feat->bf16 transcode + dst histogram
// ---------------------------------------------------------------------------
__global__ __launch_bounds__(256) void prep_kernel(
    const float* __restrict__ feat, const int* __restrict__ eidx,
    int* __restrict__ cursor, unsigned* __restrict__ fb,
    float* __restrict__ cg, int N, int E) {
    if (blockIdx.x == 0) cg_compute_block(cg);
    int t = blockIdx.x * 256 + threadIdx.x;
    if (t < N * 32) {
        int n = t >> 5, u = t & 31;
        const float* f = feat + (size_t)n * 128;
        float s = f[u];
        float vx = f[32 + 3 * u], vy = f[33 + 3 * u], vz = f[34 + 3 * u];
        ((uint2*)fb)[t] = make_uint2(bpack(s, vx), bpack(vy, vz));
    }
    if (t < E) atomicAdd(&cursor[eidx[E + t]], 1);
}

// ---------------------------------------------------------------------------
// WBT build (176 blocks): WBT[j][k], k = t*32+u.
//   j<32 (out0): t0 -> cg0*w0, t1 -> w3
//   j>=32: w=(j-32)/3, m=(j-32)%3: t2+mm -> (mm==m)*w1 ;
//   t5+i -> c2[i][m]*w2 ; t8+mm -> (mm==m)*w4
// ---------------------------------------------------------------------------
__global__ __launch_bounds__(256) void wbt_kernel(
    const float* __restrict__ W, const float* __restrict__ cg,
    unsigned short* __restrict__ WBT) {
    int idx = blockIdx.x * 256 + threadIdx.x;
    if (idx >= 128 * 352) return;
    int j = idx / 352, k = idx % 352;
    int t = k >> 5, u = k & 31;
    float val = 0.f;
    if (j < 32) {
        if (t == 0) val = cg[0] * W[u * 32 + j];
        else if (t == 1) val = W[3072 + u * 32 + j];
    } else {
        int w = (j - 32) / 3, m = (j - 32) % 3;
        if (t >= 2 && t <= 4) { if (t - 2 == m) val = W[1024 + u * 32 + w]; }
        else if (t >= 5 && t <= 7) { val = cg[10 + (t - 5) * 3 + m] * W[2048 + u * 32 + w]; }
        else if (t >= 8) { if (t - 8 == m) val = W[4096 + u * 32 + w]; }
    }
    WBT[idx] = bh(val);
}

// ---------------------------------------------------------------------------
// 3-pass coalesced hierarchical scan (N <= 256*256)
// ---------------------------------------------------------------------------
__global__ __launch_bounds__(256) void scanA_kernel(
    const int* __restrict__ counts, int* __restrict__ tilesums, int N) {
    __shared__ int lds[4];
    int i = blockIdx.x * 256 + threadIdx.x;
    int v = (i < N) ? counts[i] : 0;
#pragma unroll
    for (int d = 1; d < 64; d <<= 1) v += __shfl_xor(v, d);
    int wid = threadIdx.x >> 6;
    if ((threadIdx.x & 63) == 0) lds[wid] = v;
    __syncthreads();
    if (threadIdx.x == 0)
        tilesums[blockIdx.x] = lds[0] + lds[1] + lds[2] + lds[3];
}

__global__ __launch_bounds__(256) void scanB_kernel(
    int* __restrict__ tilesums, int tiles) {
    __shared__ int lds[4];
    int tid = threadIdx.x;
    int v = (tid < tiles) ? tilesums[tid] : 0;
    int orig = v;
#pragma unroll
    for (int d = 1; d < 64; d <<= 1) {
        int t = __shfl_up(v, d);
        if ((tid & 63) >= d) v += t;
    }
    int wid = tid >> 6;
    if ((tid & 63) == 63) lds[wid] = v;
    __syncthreads();
    int base = 0;
    for (int q = 0; q < wid; ++q) base += lds[q];
    if (tid < tiles) tilesums[tid] = base + v - orig;  // exclusive
}

__global__ __launch_bounds__(256) void scanC_kernel(
    int* __restrict__ counts, const int* __restrict__ tilesums, int N) {
    __shared__ int lds[4];
    int i = blockIdx.x * 256 + threadIdx.x;
    int tid = threadIdx.x;
    int v = (i < N) ? counts[i] : 0;
    int orig = v;
#pragma unroll
    for (int d = 1; d < 64; d <<= 1) {
        int t = __shfl_up(v, d);
        if ((tid & 63) >= d) v += t;
    }
    int wid = tid >> 6;
    if ((tid & 63) == 63) lds[wid] = v;
    __syncthreads();
    int base = tilesums[blockIdx.x];
    for (int q = 0; q < wid; ++q) base += lds[q];
    if (i < N) counts[i] = base + v - orig;  // exclusive prefix
}

// ---------------------------------------------------------------------------
// zscatter: per edge compute 16 lane-invariant values (CG (x) Y folded),
// write one 40B (8B-aligned) record at the dst-sorted position.
// ---------------------------------------------------------------------------
__global__ __launch_bounds__(256) void zscatter_kernel(
    const int* __restrict__ eidx, const float* __restrict__ sh,
    const float* __restrict__ cg, int* __restrict__ cursor,
    unsigned* __restrict__ zrec, int E) {
    int t = blockIdx.x * 256 + threadIdx.x;
    if (t >= E) return;
    int src = eidx[t];
    int dst = eidx[E + t];
    int pos = atomicAdd(&cursor[dst], 1);
    const float* Ye = sh + (size_t)t * 9;
    float Y0 = Ye[0];
    float Y1v[3] = {Ye[1], Ye[2], Ye[3]};
    float Y2v[5] = {Ye[4], Ye[5], Ye[6], Ye[7], Ye[8]};
    float Z1[3], Z3[3], Z4[9];
#pragma unroll
    for (int m = 0; m < 3; ++m)
        Z1[m] = fmaf(Y1v[0], cg[1 + m],
                fmaf(Y1v[1], cg[4 + m], Y1v[2] * cg[7 + m]));
#pragma unroll
    for (int i = 0; i < 3; ++i)
        Z3[i] = fmaf(Y1v[0], cg[19 + i * 3],
                fmaf(Y1v[1], cg[19 + i * 3 + 1], Y1v[2] * cg[19 + i * 3 + 2]));
#pragma unroll
    for (int i = 0; i < 3; ++i)
#pragma unroll
        for (int m = 0; m < 3; ++m) {
            float acc = 0.f;
#pragma unroll
            for (int j = 0; j < 5; ++j)
                acc = fmaf(Y2v[j], cg[28 + (i * 5 + j) * 3 + m], acc);
            Z4[i * 3 + m] = acc;
        }
    uint2* rec = (uint2*)(zrec + (size_t)pos * 10);
    rec[0] = make_uint2((unsigned)src, bpack(Y0, Z1[0]));
    rec[1] = make_uint2(bpack(Z1[1], Z1[2]), bpack(Z3[0], Z3[1]));
    rec[2] = make_uint2(bpack(Z3[2], Z4[0]), bpack(Z4[1], Z4[2]));
    rec[3] = make_uint2(bpack(Z4[3], Z4[4]), bpack(Z4[5], Z4[6]));
    rec[4] = make_uint2(bpack(Z4[7], Z4[8]), 0u);
}
// After zscatter: cursor[d] == end of d's range.

// ---------------------------------------------------------------------------
// Gather (u-space): one wave per dst; lane owns u = lane&31; halves take
// alternate edges. 19 FMA/edge/lane into 11 accumulators; shfl combine;
// 11 coalesced ushort stores to G[n][t][u]. No LDS, no W.
// ---------------------------------------------------------------------------
__global__ __launch_bounds__(256) void gather_kernel(
    const unsigned* __restrict__ fb, const unsigned* __restrict__ zrec,
    const int* __restrict__ cursor, unsigned short* __restrict__ G, int N) {
    int wave = (blockIdx.x * 256 + threadIdx.x) >> 6;
    int lane = threadIdx.x & 63;
    if (wave >= N) return;
    int start = wave ? cursor[wave - 1] : 0;
    int end = cursor[wave];
    int half = lane >> 5, u = lane & 31;

    float g0 = 0.f, g3 = 0.f;
    float g1x = 0.f, g1y = 0.f, g1z = 0.f;
    float g2x = 0.f, g2y = 0.f, g2z = 0.f;
    float g4x = 0.f, g4y = 0.f, g4z = 0.f;

    for (int idx = start + half; idx < end; idx += 2) {
        const uint2* r = (const uint2*)(zrec + (size_t)idx * 10);
        uint2 r0 = r[0], r1 = r[1], r2 = r[2], r3 = r[3], r4 = r[4];
        int src = (int)r0.x;
        uint2 f2 = ((const uint2*)fb)[(size_t)src * 32 + u];
        float s = blo(f2.x), vx = bhi(f2.x);
        float vy = blo(f2.y), vz = bhi(f2.y);
        float y0 = blo(r0.y), z10 = bhi(r0.y);
        float z11 = blo(r1.x), z12 = bhi(r1.x);
        float z30 = blo(r1.y), z31 = bhi(r1.y);
        float z32 = blo(r2.x), z400 = bhi(r2.x);
        float z401 = blo(r2.y), z402 = bhi(r2.y);
        float z410 = blo(r3.x), z411 = bhi(r3.x);
        float z412 = blo(r3.y), z420 = bhi(r3.y);
        float z421 = blo(r4.x), z422 = bhi(r4.x);

        g0 = fmaf(y0, s, g0);
        g1x = fmaf(z10, s, g1x); g1y = fmaf(z11, s, g1y); g1z = fmaf(z12, s, g1z);
        g2x = fmaf(y0, vx, g2x); g2y = fmaf(y0, vy, g2y); g2z = fmaf(y0, vz, g2z);
        g3 = fmaf(z30, vx, fmaf(z31, vy, fmaf(z32, vz, g3)));
        g4x = fmaf(vx, z400, fmaf(vy, z410, fmaf(vz, z420, g4x)));
        g4y = fmaf(vx, z401, fmaf(vy, z411, fmaf(vz, z421, g4y)));
        g4z = fmaf(vx, z402, fmaf(vy, z412, fmaf(vz, z422, g4z)));
    }
    g0 += __shfl_xor(g0, 32);  g3 += __shfl_xor(g3, 32);
    g1x += __shfl_xor(g1x, 32); g1y += __shfl_xor(g1y, 32); g1z += __shfl_xor(g1z, 32);
    g2x += __shfl_xor(g2x, 32); g2y += __shfl_xor(g2y, 32); g2z += __shfl_xor(g2z, 32);
    g4x += __shfl_xor(g4x, 32); g4y += __shfl_xor(g4y, 32); g4z += __shfl_xor(g4z, 32);

    if (half == 0) {
        unsigned short* Gr = G + (size_t)wave * 352 + u;
        Gr[0] = bh(g0);         // t=0
        Gr[32] = bh(g3);        // t=1
        Gr[64] = bh(g1x);  Gr[96] = bh(g1y);  Gr[128] = bh(g1z);
        Gr[160] = bh(g2x); Gr[192] = bh(g2y); Gr[224] = bh(g2z);
        Gr[256] = bh(g4x); Gr[288] = bh(g4y); Gr[320] = bh(g4z);
    }
}

// ---------------------------------------------------------------------------
// Epilogue: out[n][j] = Sum_k G[n][k]*WBT[j][k] via mfma_f32_16x16x32_bf16.
// One wave per 16-dst tile; A-frags (K=352 -> 11) held in regs across the 8
// j-tiles. D: lane l reg i -> out[n0+(l>>4)*4+i][jt*16+(l&15)].
// ---------------------------------------------------------------------------
__global__ __launch_bounds__(256) void epilogue_kernel(
    const unsigned short* __restrict__ G, const unsigned short* __restrict__ WBT,
    float* __restrict__ out, int N) {
    int wid = (blockIdx.x * 256 + threadIdx.x) >> 6;
    int lane = threadIdx.x & 63;
    int ntiles = N >> 4;
    if (wid >= ntiles) return;
    int n0 = wid << 4;
    int r = lane & 15, q = lane >> 4;

    bf16x8 a[11];
#pragma unroll
    for (int kk = 0; kk < 11; ++kk)
        a[kk] = *(const bf16x8*)(G + (size_t)(n0 + r) * 352 + kk * 32 + q * 8);

#pragma unroll
    for (int jt = 0; jt < 8; ++jt) {
        f32x4 acc = {0.f, 0.f, 0.f, 0.f};
#pragma unroll
        for (int kk = 0; kk < 11; ++kk) {
            bf16x8 b = *(const bf16x8*)(WBT + (size_t)(jt * 16 + r) * 352 + kk * 32 + q * 8);
            acc = __builtin_amdgcn_mfma_f32_16x16x32_bf16(a[kk], b, acc, 0, 0, 0);
        }
#pragma unroll
        for (int i = 0; i < 4; ++i)
            out[(size_t)(n0 + q * 4 + i) * 128 + jt * 16 + r] = acc[i];
    }
}

extern "C" void kernel_launch(void* const* d_in, const int* in_sizes, int n_in,
                              void* d_out, int out_size, void* d_ws, size_t ws_size,
                              hipStream_t stream) {
    const float* feat = (const float*)d_in[0];
    const float* sh = (const float*)d_in[1];
    const int* eidx = (const int*)d_in[2];
    const float* W = (const float*)d_in[3];
    float* out = (float*)d_out;
    int N = in_sizes[0] / 128;
    int E = in_sizes[1] / 9;

    float* wsf = (float*)d_ws;
    float* cg = wsf;                                       // 128 words
    int* cursor = (int*)(wsf + 128);                       // N words
    size_t off = (size_t)(128 + N + 1) & ~(size_t)1;       // 8B align
    unsigned* zrec = (unsigned*)(wsf + off);               // 10E words
    unsigned* fb = zrec + (size_t)10 * E;                  // 64N words
    unsigned short* G = (unsigned short*)(fb + (size_t)64 * N);  // 176N words
    unsigned short* WBT = G + (size_t)352 * N;             // 22528 words (ushort)
    int* tilesums = (int*)(WBT + 45056);                   // 256 words

    int tiles = (N + 255) / 256;

    hipMemsetAsync(cursor, 0, (size_t)N * sizeof(int), stream);
    prep_kernel<<<(N * 32 + 255) / 256, 256, 0, stream>>>(feat, eidx, cursor, fb, cg, N, E);
    wbt_kernel<<<176, 256, 0, stream>>>(W, cg, WBT);
    scanA_kernel<<<tiles, 256, 0, stream>>>(cursor, tilesums, N);
    scanB_kernel<<<1, 256, 0, stream>>>(tilesums, tiles);
    scanC_kernel<<<tiles, 256, 0, stream>>>(cursor, tilesums, N);
    zscatter_kernel<<<(E + 255) / 256, 256, 0, stream>>>(eidx, sh, cg, cursor, zrec, E);
    gather_kernel<<<(N * 64 + 255) / 256, 256, 0, stream>>>(fb, zrec, cursor, G, N);
    epilogue_kernel<<<((N >> 4) * 64 + 255) / 256, 256, 0, stream>>>(G, WBT, out, N);
}

// Round 9
// 191.359 us; speedup vs baseline: 1.7521x; 1.0456x over previous
//
#include <hip/hip_runtime.h>
#include <math.h>

// ---------------------------------------------------------------------------
// u-space aggregation + MFMA epilogue.
//   gather:  G[n][t][u] = Sum_{e->n} z_t(Y_e) (x) feat_u[src_e]   (bf16, K=352)
//   epilog:  out[n][j]  = Sum_k G[n][k] * WB[j][k]   (16x16x32 bf16 MFMA)
// Workspace (4B words):
//   cg      [0..128)        CG tensors (alpha/norm folded)
//   cursor  [128 .. +N)     memset0 -> hist -> prefix -> cursor -> row ends
//   zrec    [.. +10E)       dst-sorted 40B records (8B aligned)
//   fb      [.. +64N)       feat bf16 [N][32] uint2 {P(s,vx),P(vy,vz)}
//   G       [.. +176N)      ushort [N][352], k = t*32+u
//   WBT     [.. +22528)     ushort [128][352]  (W bf16, cg0/c2 folded)
//   tilesums[.. +256)       per-tile sums for hierarchical scan
// ---------------------------------------------------------------------------

typedef __attribute__((ext_vector_type(8))) short bf16x8;
typedef __attribute__((ext_vector_type(4))) float f32x4;

__device__ inline float blo(unsigned u) { return __uint_as_float(u << 16); }
__device__ inline float bhi(unsigned u) { return __uint_as_float(u & 0xffff0000u); }
__device__ inline unsigned bpack(float a, float b) {
    unsigned ua = __float_as_uint(a);
    ua = (ua + 0x7fffu + ((ua >> 16) & 1u)) >> 16;
    unsigned ub = __float_as_uint(b);
    ub = (ub + 0x7fffu + ((ub >> 16) & 1u)) & 0xffff0000u;
    return ua | ub;
}
__device__ inline unsigned short bh(float a) {
    unsigned ua = __float_as_uint(a);
    return (unsigned short)((ua + 0x7fffu + ((ua >> 16) & 1u)) >> 16);
}

// All CG math in f32: every factorial involved is <= 120 (exact in f32) and
// downstream values are bf16-rounded, so f64 (50x slower div/sqrt) is waste.
__device__ inline float dfactf(int n) {
    float r = 1.0f;
    for (int i = 2; i <= n; ++i) r *= (float)i;
    return r;
}

// real->complex spherical harmonic change of basis (e3nn convention)
__device__ void qmatf(int l, float qr[5][5], float qi[5][5]) {
    for (int a = 0; a < 5; a++)
        for (int b = 0; b < 5; b++) { qr[a][b] = 0.0f; qi[a][b] = 0.0f; }
    const float inv = 0.70710678118654752440f;
    for (int m = -l; m < 0; ++m) {
        qr[l + m][l - m] = inv;
        qi[l + m][l + m] = -inv;
    }
    qr[l][l] = 1.0f;
    for (int m = 1; m <= l; ++m) {
        float sgn = (m & 1) ? -1.0f : 1.0f;
        qr[l + m][l + m] = sgn * inv;
        qi[l + m][l - m] = sgn * inv;
    }
    if (l == 1) {          // * (-i)
        for (int a = 0; a < 5; a++)
            for (int b = 0; b < 5; b++) {
                float r = qr[a][b], im = qi[a][b];
                qr[a][b] = im; qi[a][b] = -r;
            }
    } else if (l == 2) {   // * (-1)
        for (int a = 0; a < 5; a++)
            for (int b = 0; b < 5; b++) { qr[a][b] = -qr[a][b]; qi[a][b] = -qi[a][b]; }
    }
}

// SU(2) "CG" element via the reference's exact Racah-form (all six m-dependent
// factorials in the NUMERATOR — non-standard but matches the reference).
__device__ float su2_cg_elem_f(int l1, int l2, int l3, int i, int k, int n) {
    int m1 = i - l1, m2 = k - l2, m3 = n - l3;
    if (m1 + m2 != m3) return 0.0f;
    int vmin = -l1 + l2 + m3;
    if (-l1 + m1 > vmin) vmin = -l1 + m1;
    if (0 > vmin) vmin = 0;
    int vmax = l2 + l3 + m1;
    if (l3 - l1 + l2 < vmax) vmax = l3 - l1 + l2;
    if (l3 + m3 < vmax) vmax = l3 + m3;
    if (vmax < vmin) return 0.0f;
    float c = sqrtf((float)(2 * l3 + 1) * dfactf(l3 + l1 - l2) *
                    dfactf(l3 - l1 + l2) * dfactf(l1 + l2 - l3) /
                    dfactf(l1 + l2 + l3 + 1));
    c *= sqrtf(dfactf(l3 + m3) * dfactf(l3 - m3) * dfactf(l1 - m1) *
               dfactf(l1 + m1) * dfactf(l2 - m2) * dfactf(l2 + m2));
    float s = 0.0f;
    for (int v = vmin; v <= vmax; ++v) {
        float term = dfactf(l2 + l3 + m1 - v) * dfactf(l1 - m1 + v) /
                     (dfactf(v) * dfactf(l3 - l1 + l2 - v) *
                      dfactf(l3 + m3 - v) * dfactf(v + l1 - l2 - m3));
        if ((v + l2 + m2) & 1) term = -term;
        s += term;
    }
    return c * s;
}

// cg compute by one 256-thread block (thread t -> path p=t/45, element t%45)
__device__ void cg_compute_block(float* __restrict__ cg_out) {
    const int l1s[5] = {0, 0, 1, 1, 1};
    const int l2s[5] = {0, 1, 0, 1, 2};
    const int l3s[5] = {0, 1, 1, 0, 1};
    const int offs[5] = {0, 1, 10, 19, 28};
    const float alphas[5] = {0.125f, 0.10206207261596575f, 0.10206207261596575f,
                             0.125f, 0.10206207261596575f};
    __shared__ float vals[5][45];
    int t = threadIdx.x;
    int p = t / 45, idx = t % 45;
    bool active = (t < 225);
    float acc = 0.0f;
    int d1 = 0, d2 = 0, d3 = 0;
    if (active) {
        int l1 = l1s[p], l2 = l2s[p], l3 = l3s[p];
        d1 = 2 * l1 + 1; d2 = 2 * l2 + 1; d3 = 2 * l3 + 1;
        if (idx < d1 * d2 * d3) {
            int j = idx / (d2 * d3);
            int rem = idx % (d2 * d3);
            int l_ = rem / d3, m = rem % d3;
            float q1r[5][5], q1i[5][5], q2r[5][5], q2i[5][5], q3r[5][5], q3i[5][5];
            qmatf(l1, q1r, q1i);
            qmatf(l2, q2r, q2i);
            qmatf(l3, q3r, q3i);
            for (int i = 0; i < d1; ++i)
                for (int k = 0; k < d2; ++k)
                    for (int n = 0; n < d3; ++n) {
                        float C = su2_cg_elem_f(l1, l2, l3, i, k, n);
                        if (C == 0.0f) continue;
                        float ar = q1r[i][j], ai = q1i[i][j];
                        float br = q2r[k][l_], bi = q2i[k][l_];
                        float cr = q3r[n][m], ci = q3i[n][m];
                        float abr = ar * br - ai * bi;
                        float abi = ar * bi + ai * br;
                        acc += (abr * cr + abi * ci) * C;  // Re(a*b*conj(c))
                    }
        }
        vals[p][idx] = acc;
    }
    __syncthreads();
    if (active && idx < d1 * d2 * d3) {
        float n2 = 0.0f;
        for (int q = 0; q < 45; ++q) n2 += vals[p][q] * vals[p][q];
        cg_out[offs[p] + idx] = acc * alphas[p] / sqrtf(n2);
    }
}

// ---------------------------------------------------------------------------
// prep: cg (block 0, f32, ~2us) + feat->bf16 transcode + dst histogram
// ---------------------------------------------------------------------------
__global__ __launch_bounds__(256) void prep_kernel(
    const float* __restrict__ feat, const int* __restrict__ eidx,
    int* __restrict__ cursor, unsigned* __restrict__ fb,
    float* __restrict__ cg, int N, int E) {
    if (blockIdx.x == 0) cg_compute_block(cg);
    int t = blockIdx.x * 256 + threadIdx.x;
    if (t < N * 32) {
        int n = t >> 5, u = t & 31;
        const float* f = feat + (size_t)n * 128;
        float s = f[u];
        float vx = f[32 + 3 * u], vy = f[33 + 3 * u], vz = f[34 + 3 * u];
        ((uint2*)fb)[t] = make_uint2(bpack(s, vx), bpack(vy, vz));
    }
    if (t < E) atomicAdd(&cursor[eidx[E + t]], 1);
}

// ---------------------------------------------------------------------------
// scanA (fused with WBT build; scanA grid 196 blocks >= 176 wbt blocks)
// WBT[j][k], k = t*32+u:  j<32 (out0): t0 -> cg0*w0, t1 -> w3
//   j>=32: w=(j-32)/3, m=(j-32)%3: t2+mm -> (mm==m)*w1 ;
//   t5+i -> c2[i][m]*w2 ; t8+mm -> (mm==m)*w4
// ---------------------------------------------------------------------------
__global__ __launch_bounds__(256) void scanA_kernel(
    const int* __restrict__ counts, int* __restrict__ tilesums, int N,
    const float* __restrict__ W, const float* __restrict__ cg,
    unsigned short* __restrict__ WBT) {
    __shared__ int lds[4];
    int i = blockIdx.x * 256 + threadIdx.x;
    int v = (i < N) ? counts[i] : 0;
#pragma unroll
    for (int d = 1; d < 64; d <<= 1) v += __shfl_xor(v, d);
    int wid = threadIdx.x >> 6;
    if ((threadIdx.x & 63) == 0) lds[wid] = v;
    __syncthreads();
    if (threadIdx.x == 0)
        tilesums[blockIdx.x] = lds[0] + lds[1] + lds[2] + lds[3];
    // fused WBT build (independent work, stream-ordered after prep's cg)
    int idx = i;
    if (idx < 128 * 352) {
        int j = idx / 352, k = idx % 352;
        int t = k >> 5, u = k & 31;
        float val = 0.f;
        if (j < 32) {
            if (t == 0) val = cg[0] * W[u * 32 + j];
            else if (t == 1) val = W[3072 + u * 32 + j];
        } else {
            int w = (j - 32) / 3, m = (j - 32) % 3;
            if (t >= 2 && t <= 4) { if (t - 2 == m) val = W[1024 + u * 32 + w]; }
            else if (t >= 5 && t <= 7) { val = cg[10 + (t - 5) * 3 + m] * W[2048 + u * 32 + w]; }
            else if (t >= 8) { if (t - 8 == m) val = W[4096 + u * 32 + w]; }
        }
        WBT[idx] = bh(val);
    }
}

__global__ __launch_bounds__(256) void scanB_kernel(
    int* __restrict__ tilesums, int tiles) {
    __shared__ int lds[4];
    int tid = threadIdx.x;
    int v = (tid < tiles) ? tilesums[tid] : 0;
    int orig = v;
#pragma unroll
    for (int d = 1; d < 64; d <<= 1) {
        int t = __shfl_up(v, d);
        if ((tid & 63) >= d) v += t;
    }
    int wid = tid >> 6;
    if ((tid & 63) == 63) lds[wid] = v;
    __syncthreads();
    int base = 0;
    for (int q = 0; q < wid; ++q) base += lds[q];
    if (tid < tiles) tilesums[tid] = base + v - orig;  // exclusive
}

__global__ __launch_bounds__(256) void scanC_kernel(
    int* __restrict__ counts, const int* __restrict__ tilesums, int N) {
    __shared__ int lds[4];
    int i = blockIdx.x * 256 + threadIdx.x;
    int tid = threadIdx.x;
    int v = (i < N) ? counts[i] : 0;
    int orig = v;
#pragma unroll
    for (int d = 1; d < 64; d <<= 1) {
        int t = __shfl_up(v, d);
        if ((tid & 63) >= d) v += t;
    }
    int wid = tid >> 6;
    if ((tid & 63) == 63) lds[wid] = v;
    __syncthreads();
    int base = tilesums[blockIdx.x];
    for (int q = 0; q < wid; ++q) base += lds[q];
    if (i < N) counts[i] = base + v - orig;  // exclusive prefix
}

// ---------------------------------------------------------------------------
// zscatter: per edge compute 16 lane-invariant values (CG (x) Y folded),
// write one 40B (8B-aligned) record at the dst-sorted position.
// ---------------------------------------------------------------------------
__global__ __launch_bounds__(256) void zscatter_kernel(
    const int* __restrict__ eidx, const float* __restrict__ sh,
    const float* __restrict__ cg, int* __restrict__ cursor,
    unsigned* __restrict__ zrec, int E) {
    int t = blockIdx.x * 256 + threadIdx.x;
    if (t >= E) return;
    int src = eidx[t];
    int dst = eidx[E + t];
    int pos = atomicAdd(&cursor[dst], 1);
    const float* Ye = sh + (size_t)t * 9;
    float Y0 = Ye[0];
    float Y1v[3] = {Ye[1], Ye[2], Ye[3]};
    float Y2v[5] = {Ye[4], Ye[5], Ye[6], Ye[7], Ye[8]};
    float Z1[3], Z3[3], Z4[9];
#pragma unroll
    for (int m = 0; m < 3; ++m)
        Z1[m] = fmaf(Y1v[0], cg[1 + m],
                fmaf(Y1v[1], cg[4 + m], Y1v[2] * cg[7 + m]));
#pragma unroll
    for (int i = 0; i < 3; ++i)
        Z3[i] = fmaf(Y1v[0], cg[19 + i * 3],
                fmaf(Y1v[1], cg[19 + i * 3 + 1], Y1v[2] * cg[19 + i * 3 + 2]));
#pragma unroll
    for (int i = 0; i < 3; ++i)
#pragma unroll
        for (int m = 0; m < 3; ++m) {
            float acc = 0.f;
#pragma unroll
            for (int j = 0; j < 5; ++j)
                acc = fmaf(Y2v[j], cg[28 + (i * 5 + j) * 3 + m], acc);
            Z4[i * 3 + m] = acc;
        }
    uint2* rec = (uint2*)(zrec + (size_t)pos * 10);
    rec[0] = make_uint2((unsigned)src, bpack(Y0, Z1[0]));
    rec[1] = make_uint2(bpack(Z1[1], Z1[2]), bpack(Z3[0], Z3[1]));
    rec[2] = make_uint2(bpack(Z3[2], Z4[0]), bpack(Z4[1], Z4[2]));
    rec[3] = make_uint2(bpack(Z4[3], Z4[4]), bpack(Z4[5], Z4[6]));
    rec[4] = make_uint2(bpack(Z4[7], Z4[8]), 0u);
}
// After zscatter: cursor[d] == end of d's range.

// ---------------------------------------------------------------------------
// Gather (u-space): one wave per dst; lane owns u = lane&31; halves take
// alternate edges. 19 FMA/edge/lane into 11 accumulators; shfl combine;
// 11 coalesced ushort stores to G[n][t][u]. No LDS, no W.
// ---------------------------------------------------------------------------
__global__ __launch_bounds__(256) void gather_kernel(
    const unsigned* __restrict__ fb, const unsigned* __restrict__ zrec,
    const int* __restrict__ cursor, unsigned short* __restrict__ G, int N) {
    int wave = (blockIdx.x * 256 + threadIdx.x) >> 6;
    int lane = threadIdx.x & 63;
    if (wave >= N) return;
    int start = wave ? cursor[wave - 1] : 0;
    int end = cursor[wave];
    int half = lane >> 5, u = lane & 31;

    float g0 = 0.f, g3 = 0.f;
    float g1x = 0.f, g1y = 0.f, g1z = 0.f;
    float g2x = 0.f, g2y = 0.f, g2z = 0.f;
    float g4x = 0.f, g4y = 0.f, g4z = 0.f;

    for (int idx = start + half; idx < end; idx += 2) {
        const uint2* r = (const uint2*)(zrec + (size_t)idx * 10);
        uint2 r0 = r[0], r1 = r[1], r2 = r[2], r3 = r[3], r4 = r[4];
        int src = (int)r0.x;
        uint2 f2 = ((const uint2*)fb)[(size_t)src * 32 + u];
        float s = blo(f2.x), vx = bhi(f2.x);
        float vy = blo(f2.y), vz = bhi(f2.y);
        float y0 = blo(r0.y), z10 = bhi(r0.y);
        float z11 = blo(r1.x), z12 = bhi(r1.x);
        float z30 = blo(r1.y), z31 = bhi(r1.y);
        float z32 = blo(r2.x), z400 = bhi(r2.x);
        float z401 = blo(r2.y), z402 = bhi(r2.y);
        float z410 = blo(r3.x), z411 = bhi(r3.x);
        float z412 = blo(r3.y), z420 = bhi(r3.y);
        float z421 = blo(r4.x), z422 = bhi(r4.x);

        g0 = fmaf(y0, s, g0);
        g1x = fmaf(z10, s, g1x); g1y = fmaf(z11, s, g1y); g1z = fmaf(z12, s, g1z);
        g2x = fmaf(y0, vx, g2x); g2y = fmaf(y0, vy, g2y); g2z = fmaf(y0, vz, g2z);
        g3 = fmaf(z30, vx, fmaf(z31, vy, fmaf(z32, vz, g3)));
        g4x = fmaf(vx, z400, fmaf(vy, z410, fmaf(vz, z420, g4x)));
        g4y = fmaf(vx, z401, fmaf(vy, z411, fmaf(vz, z421, g4y)));
        g4z = fmaf(vx, z402, fmaf(vy, z412, fmaf(vz, z422, g4z)));
    }
    g0 += __shfl_xor(g0, 32);  g3 += __shfl_xor(g3, 32);
    g1x += __shfl_xor(g1x, 32); g1y += __shfl_xor(g1y, 32); g1z += __shfl_xor(g1z, 32);
    g2x += __shfl_xor(g2x, 32); g2y += __shfl_xor(g2y, 32); g2z += __shfl_xor(g2z, 32);
    g4x += __shfl_xor(g4x, 32); g4y += __shfl_xor(g4y, 32); g4z += __shfl_xor(g4z, 32);

    if (half == 0) {
        unsigned short* Gr = G + (size_t)wave * 352 + u;
        Gr[0] = bh(g0);         // t=0
        Gr[32] = bh(g3);        // t=1
        Gr[64] = bh(g1x);  Gr[96] = bh(g1y);  Gr[128] = bh(g1z);
        Gr[160] = bh(g2x); Gr[192] = bh(g2y); Gr[224] = bh(g2z);
        Gr[256] = bh(g4x); Gr[288] = bh(g4y); Gr[320] = bh(g4z);
    }
}

// ---------------------------------------------------------------------------
// Epilogue: out[n][j] = Sum_k G[n][k]*WBT[j][k] via mfma_f32_16x16x32_bf16.
// One wave per 16-dst tile; A-frags (K=352 -> 11) held in regs across the 8
// j-tiles. D: lane l reg i -> out[n0+(l>>4)*4+i][jt*16+(l&15)].
// ---------------------------------------------------------------------------
__global__ __launch_bounds__(256) void epilogue_kernel(
    const unsigned short* __restrict__ G, const unsigned short* __restrict__ WBT,
    float* __restrict__ out, int N) {
    int wid = (blockIdx.x * 256 + threadIdx.x) >> 6;
    int lane = threadIdx.x & 63;
    int ntiles = N >> 4;
    if (wid >= ntiles) return;
    int n0 = wid << 4;
    int r = lane & 15, q = lane >> 4;

    bf16x8 a[11];
#pragma unroll
    for (int kk = 0; kk < 11; ++kk)
        a[kk] = *(const bf16x8*)(G + (size_t)(n0 + r) * 352 + kk * 32 + q * 8);

#pragma unroll
    for (int jt = 0; jt < 8; ++jt) {
        f32x4 acc = {0.f, 0.f, 0.f, 0.f};
#pragma unroll
        for (int kk = 0; kk < 11; ++kk) {
            bf16x8 b = *(const bf16x8*)(WBT + (size_t)(jt * 16 + r) * 352 + kk * 32 + q * 8);
            acc = __builtin_amdgcn_mfma_f32_16x16x32_bf16(a[kk], b, acc, 0, 0, 0);
        }
#pragma unroll
        for (int i = 0; i < 4; ++i)
            out[(size_t)(n0 + q * 4 + i) * 128 + jt * 16 + r] = acc[i];
    }
}

extern "C" void kernel_launch(void* const* d_in, const int* in_sizes, int n_in,
                              void* d_out, int out_size, void* d_ws, size_t ws_size,
                              hipStream_t stream) {
    const float* feat = (const float*)d_in[0];
    const float* sh = (const float*)d_in[1];
    const int* eidx = (const int*)d_in[2];
    const float* W = (const float*)d_in[3];
    float* out = (float*)d_out;
    int N = in_sizes[0] / 128;
    int E = in_sizes[1] / 9;

    float* wsf = (float*)d_ws;
    float* cg = wsf;                                       // 128 words
    int* cursor = (int*)(wsf + 128);                       // N words
    size_t off = (size_t)(128 + N + 1) & ~(size_t)1;       // 8B align
    unsigned* zrec = (unsigned*)(wsf + off);               // 10E words
    unsigned* fb = zrec + (size_t)10 * E;                  // 64N words
    unsigned short* G = (unsigned short*)(fb + (size_t)64 * N);  // 176N words
    unsigned short* WBT = G + (size_t)352 * N;             // 22528 words (ushort)
    int* tilesums = (int*)(WBT + 45056);                   // 256 words

    int tiles = (N + 255) / 256;

    hipMemsetAsync(cursor, 0, (size_t)N * sizeof(int), stream);
    prep_kernel<<<(N * 32 + 255) / 256, 256, 0, stream>>>(feat, eidx, cursor, fb, cg, N, E);
    scanA_kernel<<<tiles, 256, 0, stream>>>(cursor, tilesums, N, W, cg, WBT);
    scanB_kernel<<<1, 256, 0, stream>>>(tilesums, tiles);
    scanC_kernel<<<tiles, 256, 0, stream>>>(cursor, tilesums, N);
    zscatter_kernel<<<(E + 255) / 256, 256, 0, stream>>>(eidx, sh, cg, cursor, zrec, E);
    gather_kernel<<<(N * 64 + 255) / 256, 256, 0, stream>>>(fb, zrec, cursor, G, N);
    epilogue_kernel<<<((N >> 4) * 64 + 255) / 256, 256, 0, stream>>>(G, WBT, out, N);
}

// Round 10
// 185.964 us; speedup vs baseline: 1.8029x; 1.0290x over previous
//
#include <hip/hip_runtime.h>
#include <math.h>

// ---------------------------------------------------------------------------
// u-space aggregation + MFMA epilogue.
//   gather:  G[n][t][u] = Sum_{e->n} z_t(Y_e) (x) feat_u[src_e]   (bf16, K=352)
//   epilog:  out[n][j]  = Sum_k G[n][k] * WB[j][k]   (16x16x32 bf16 MFMA)
// Workspace (4B words):
//   cg      [0..128)        CG tensors (alpha/norm folded)
//   cursor  [128 .. +N)     memset0 -> hist -> prefix -> cursor -> row ends
//   zrec    [.. +10E)       dst-sorted 40B records (8B aligned)
//   fb      [.. +64N)       feat bf16 [N][32] uint2 {P(s,vx),P(vy,vz)}
//   G       [.. +176N)      ushort [N][352], k = t*32+u
//   WBT     [.. +22528)     ushort [128][352]  (W bf16, cg0/c2 folded)
//   tilesums[.. +256)       per-tile sums for hierarchical scan
// ---------------------------------------------------------------------------

typedef __attribute__((ext_vector_type(8))) short bf16x8;
typedef __attribute__((ext_vector_type(4))) float f32x4;

__device__ inline float blo(unsigned u) { return __uint_as_float(u << 16); }
__device__ inline float bhi(unsigned u) { return __uint_as_float(u & 0xffff0000u); }
__device__ inline unsigned bpack(float a, float b) {
    unsigned ua = __float_as_uint(a);
    ua = (ua + 0x7fffu + ((ua >> 16) & 1u)) >> 16;
    unsigned ub = __float_as_uint(b);
    ub = (ub + 0x7fffu + ((ub >> 16) & 1u)) & 0xffff0000u;
    return ua | ub;
}
__device__ inline unsigned short bh(float a) {
    unsigned ua = __float_as_uint(a);
    return (unsigned short)((ua + 0x7fffu + ((ua >> 16) & 1u)) >> 16);
}

// f32 factorial (all n <= 7 here; exact in f32). Register-only scalar loop.
__device__ inline float dfactf(int n) {
    float r = 1.0f;
    for (int i = 2; i <= n; ++i) r *= (float)i;
    return r;
}

// SU(2) "CG" element via the reference's exact Racah-form (all six m-dependent
// factorials in the NUMERATOR — non-standard but matches the reference).
// No arrays -> no scratch.
__device__ float su2_cg_elem_f(int l1, int l2, int l3, int i, int k, int n) {
    int m1 = i - l1, m2 = k - l2, m3 = n - l3;
    if (m1 + m2 != m3) return 0.0f;
    int vmin = -l1 + l2 + m3;
    if (-l1 + m1 > vmin) vmin = -l1 + m1;
    if (0 > vmin) vmin = 0;
    int vmax = l2 + l3 + m1;
    if (l3 - l1 + l2 < vmax) vmax = l3 - l1 + l2;
    if (l3 + m3 < vmax) vmax = l3 + m3;
    if (vmax < vmin) return 0.0f;
    float c = sqrtf((float)(2 * l3 + 1) * dfactf(l3 + l1 - l2) *
                    dfactf(l3 - l1 + l2) * dfactf(l1 + l2 - l3) /
                    dfactf(l1 + l2 + l3 + 1));
    c *= sqrtf(dfactf(l3 + m3) * dfactf(l3 - m3) * dfactf(l1 - m1) *
               dfactf(l1 + m1) * dfactf(l2 - m2) * dfactf(l2 + m2));
    float s = 0.0f;
    for (int v = vmin; v <= vmax; ++v) {
        float term = dfactf(l2 + l3 + m1 - v) * dfactf(l1 - m1 + v) /
                     (dfactf(v) * dfactf(l3 - l1 + l2 - v) *
                      dfactf(l3 + m3 - v) * dfactf(v + l1 - l2 - m3));
        if ((v + l2 + m2) & 1) term = -term;
        s += term;
    }
    return c * s;
}

// cg compute by one 256-thread block. CRITICAL: all dynamically-indexed
// arrays live in LDS (runtime-indexed private arrays go to SCRATCH on
// gfx950 -> ~500-cyc round trips; this was a 110us single-block straggler).
__device__ void cg_compute_block(float* __restrict__ cg_out) {
    __shared__ float sqr[3][5][5], sqi[3][5][5];  // q matrices for l=0,1,2
    __shared__ float vals[5][45];
    int t = threadIdx.x;
    // Fill q element-wise: thread t<75 -> (l=t/25, a=(t%25)/5, b=t%5).
    // Exact port of the reference's qmat (e3nn real->complex basis, * (-i)^l).
    if (t < 75) {
        int l = t / 25, a = (t % 25) / 5, b = t % 5;
        float re = 0.f, im = 0.f;
        const float inv = 0.70710678118654752440f;
        int m = a - l;
        if (a < 5 && b < 5) {
            if (m < 0) {
                if (b == l - m) re = inv;        // col l+|m|
                if (b == l + m) im = -inv;       // col l-|m|
            } else if (m == 0) {
                if (b == l && a == l) re = 1.f;
            } else {
                float sgn = (m & 1) ? -1.f : 1.f;
                if (b == l + m) re = sgn * inv;
                if (b == l - m) im = sgn * inv;
            }
        }
        // multiply by (-i)^l
        if (l == 1) { float r = re; re = im; im = -r; }
        else if (l == 2) { re = -re; im = -im; }
        sqr[l][a][b] = re;
        sqi[l][a][b] = im;
    }
    __syncthreads();
    const int l1s[5] = {0, 0, 1, 1, 1};
    const int l2s[5] = {0, 1, 0, 1, 2};
    const int l3s[5] = {0, 1, 1, 0, 1};
    const int offs[5] = {0, 1, 10, 19, 28};
    const float alphas[5] = {0.125f, 0.10206207261596575f, 0.10206207261596575f,
                             0.125f, 0.10206207261596575f};
    int p = t / 45, idx = t % 45;
    bool active = (t < 225);
    float acc = 0.0f;
    int d1 = 0, d2 = 0, d3 = 0;
    int l1 = 0, l2 = 0, l3 = 0;
    if (active) {
        l1 = l1s[p]; l2 = l2s[p]; l3 = l3s[p];
        d1 = 2 * l1 + 1; d2 = 2 * l2 + 1; d3 = 2 * l3 + 1;
        if (idx < d1 * d2 * d3) {
            int j = idx / (d2 * d3);
            int rem = idx % (d2 * d3);
            int l_ = rem / d3, m = rem % d3;
            for (int i = 0; i < d1; ++i)
                for (int k = 0; k < d2; ++k)
                    for (int n = 0; n < d3; ++n) {
                        float C = su2_cg_elem_f(l1, l2, l3, i, k, n);
                        if (C == 0.0f) continue;
                        float ar = sqr[l1][i][j], ai = sqi[l1][i][j];
                        float br = sqr[l2][k][l_], bi = sqi[l2][k][l_];
                        float cr = sqr[l3][n][m], ci = sqi[l3][n][m];
                        float abr = ar * br - ai * bi;
                        float abi = ar * bi + ai * br;
                        acc += (abr * cr + abi * ci) * C;  // Re(a*b*conj(c))
                    }
        }
        vals[p][idx] = acc;
    }
    __syncthreads();
    if (active && idx < d1 * d2 * d3) {
        float n2 = 0.0f;
        for (int q = 0; q < 45; ++q) n2 += vals[p][q] * vals[p][q];
        cg_out[offs[p] + idx] = acc * alphas[p] / sqrtf(n2);
    }
}

// ---------------------------------------------------------------------------
// prep: cg (block 0, LDS-based, ~3us) + feat->bf16 transcode + dst histogram
// ---------------------------------------------------------------------------
__global__ __launch_bounds__(256) void prep_kernel(
    const float* __restrict__ feat, const int* __restrict__ eidx,
    int* __restrict__ cursor, unsigned* __restrict__ fb,
    float* __restrict__ cg, int N, int E) {
    if (blockIdx.x == 0) cg_compute_block(cg);
    int t = blockIdx.x * 256 + threadIdx.x;
    if (t < N * 32) {
        int n = t >> 5, u = t & 31;
        const float* f = feat + (size_t)n * 128;
        float s = f[u];
        float vx = f[32 + 3 * u], vy = f[33 + 3 * u], vz = f[34 + 3 * u];
        ((uint2*)fb)[t] = make_uint2(bpack(s, vx), bpack(vy, vz));
    }
    if (t < E) atomicAdd(&cursor[eidx[E + t]], 1);
}

// ---------------------------------------------------------------------------
// scanA (fused with WBT build; scanA grid 196 blocks >= 176 wbt blocks)
// WBT[j][k], k = t*32+u:  j<32 (out0): t0 -> cg0*w0, t1 -> w3
//   j>=32: w=(j-32)/3, m=(j-32)%3: t2+mm -> (mm==m)*w1 ;
//   t5+i -> c2[i][m]*w2 ; t8+mm -> (mm==m)*w4
// ---------------------------------------------------------------------------
__global__ __launch_bounds__(256) void scanA_kernel(
    const int* __restrict__ counts, int* __restrict__ tilesums, int N,
    const float* __restrict__ W, const float* __restrict__ cg,
    unsigned short* __restrict__ WBT) {
    __shared__ int lds[4];
    int i = blockIdx.x * 256 + threadIdx.x;
    int v = (i < N) ? counts[i] : 0;
#pragma unroll
    for (int d = 1; d < 64; d <<= 1) v += __shfl_xor(v, d);
    int wid = threadIdx.x >> 6;
    if ((threadIdx.x & 63) == 0) lds[wid] = v;
    __syncthreads();
    if (threadIdx.x == 0)
        tilesums[blockIdx.x] = lds[0] + lds[1] + lds[2] + lds[3];
    // fused WBT build (independent work, stream-ordered after prep's cg)
    int idx = i;
    if (idx < 128 * 352) {
        int j = idx / 352, k = idx % 352;
        int t = k >> 5, u = k & 31;
        float val = 0.f;
        if (j < 32) {
            if (t == 0) val = cg[0] * W[u * 32 + j];
            else if (t == 1) val = W[3072 + u * 32 + j];
        } else {
            int w = (j - 32) / 3, m = (j - 32) % 3;
            if (t >= 2 && t <= 4) { if (t - 2 == m) val = W[1024 + u * 32 + w]; }
            else if (t >= 5 && t <= 7) { val = cg[10 + (t - 5) * 3 + m] * W[2048 + u * 32 + w]; }
            else if (t >= 8) { if (t - 8 == m) val = W[4096 + u * 32 + w]; }
        }
        WBT[idx] = bh(val);
    }
}

__global__ __launch_bounds__(256) void scanB_kernel(
    int* __restrict__ tilesums, int tiles) {
    __shared__ int lds[4];
    int tid = threadIdx.x;
    int v = (tid < tiles) ? tilesums[tid] : 0;
    int orig = v;
#pragma unroll
    for (int d = 1; d < 64; d <<= 1) {
        int t = __shfl_up(v, d);
        if ((tid & 63) >= d) v += t;
    }
    int wid = tid >> 6;
    if ((tid & 63) == 63) lds[wid] = v;
    __syncthreads();
    int base = 0;
    for (int q = 0; q < wid; ++q) base += lds[q];
    if (tid < tiles) tilesums[tid] = base + v - orig;  // exclusive
}

__global__ __launch_bounds__(256) void scanC_kernel(
    int* __restrict__ counts, const int* __restrict__ tilesums, int N) {
    __shared__ int lds[4];
    int i = blockIdx.x * 256 + threadIdx.x;
    int tid = threadIdx.x;
    int v = (i < N) ? counts[i] : 0;
    int orig = v;
#pragma unroll
    for (int d = 1; d < 64; d <<= 1) {
        int t = __shfl_up(v, d);
        if ((tid & 63) >= d) v += t;
    }
    int wid = tid >> 6;
    if ((tid & 63) == 63) lds[wid] = v;
    __syncthreads();
    int base = tilesums[blockIdx.x];
    for (int q = 0; q < wid; ++q) base += lds[q];
    if (i < N) counts[i] = base + v - orig;  // exclusive prefix
}

// ---------------------------------------------------------------------------
// zscatter: per edge compute 16 lane-invariant values (CG (x) Y folded),
// write one 40B (8B-aligned) record at the dst-sorted position.
// ---------------------------------------------------------------------------
__global__ __launch_bounds__(256) void zscatter_kernel(
    const int* __restrict__ eidx, const float* __restrict__ sh,
    const float* __restrict__ cg, int* __restrict__ cursor,
    unsigned* __restrict__ zrec, int E) {
    int t = blockIdx.x * 256 + threadIdx.x;
    if (t >= E) return;
    int src = eidx[t];
    int dst = eidx[E + t];
    int pos = atomicAdd(&cursor[dst], 1);
    const float* Ye = sh + (size_t)t * 9;
    float Y0 = Ye[0];
    float Y1v[3] = {Ye[1], Ye[2], Ye[3]};
    float Y2v[5] = {Ye[4], Ye[5], Ye[6], Ye[7], Ye[8]};
    float Z1[3], Z3[3], Z4[9];
#pragma unroll
    for (int m = 0; m < 3; ++m)
        Z1[m] = fmaf(Y1v[0], cg[1 + m],
                fmaf(Y1v[1], cg[4 + m], Y1v[2] * cg[7 + m]));
#pragma unroll
    for (int i = 0; i < 3; ++i)
        Z3[i] = fmaf(Y1v[0], cg[19 + i * 3],
                fmaf(Y1v[1], cg[19 + i * 3 + 1], Y1v[2] * cg[19 + i * 3 + 2]));
#pragma unroll
    for (int i = 0; i < 3; ++i)
#pragma unroll
        for (int m = 0; m < 3; ++m) {
            float acc = 0.f;
#pragma unroll
            for (int j = 0; j < 5; ++j)
                acc = fmaf(Y2v[j], cg[28 + (i * 5 + j) * 3 + m], acc);
            Z4[i * 3 + m] = acc;
        }
    uint2* rec = (uint2*)(zrec + (size_t)pos * 10);
    rec[0] = make_uint2((unsigned)src, bpack(Y0, Z1[0]));
    rec[1] = make_uint2(bpack(Z1[1], Z1[2]), bpack(Z3[0], Z3[1]));
    rec[2] = make_uint2(bpack(Z3[2], Z4[0]), bpack(Z4[1], Z4[2]));
    rec[3] = make_uint2(bpack(Z4[3], Z4[4]), bpack(Z4[5], Z4[6]));
    rec[4] = make_uint2(bpack(Z4[7], Z4[8]), 0u);
}
// After zscatter: cursor[d] == end of d's range.

// ---------------------------------------------------------------------------
// Gather (u-space): one wave per dst; lane owns u = lane&31; halves take
// alternate edges. 19 FMA/edge/lane into 11 accumulators; shfl combine;
// 11 coalesced ushort stores to G[n][t][u]. No LDS, no W.
// ---------------------------------------------------------------------------
__global__ __launch_bounds__(256) void gather_kernel(
    const unsigned* __restrict__ fb, const unsigned* __restrict__ zrec,
    const int* __restrict__ cursor, unsigned short* __restrict__ G, int N) {
    int wave = (blockIdx.x * 256 + threadIdx.x) >> 6;
    int lane = threadIdx.x & 63;
    if (wave >= N) return;
    int start = wave ? cursor[wave - 1] : 0;
    int end = cursor[wave];
    int half = lane >> 5, u = lane & 31;

    float g0 = 0.f, g3 = 0.f;
    float g1x = 0.f, g1y = 0.f, g1z = 0.f;
    float g2x = 0.f, g2y = 0.f, g2z = 0.f;
    float g4x = 0.f, g4y = 0.f, g4z = 0.f;

    for (int idx = start + half; idx < end; idx += 2) {
        const uint2* r = (const uint2*)(zrec + (size_t)idx * 10);
        uint2 r0 = r[0], r1 = r[1], r2 = r[2], r3 = r[3], r4 = r[4];
        int src = (int)r0.x;
        uint2 f2 = ((const uint2*)fb)[(size_t)src * 32 + u];
        float s = blo(f2.x), vx = bhi(f2.x);
        float vy = blo(f2.y), vz = bhi(f2.y);
        float y0 = blo(r0.y), z10 = bhi(r0.y);
        float z11 = blo(r1.x), z12 = bhi(r1.x);
        float z30 = blo(r1.y), z31 = bhi(r1.y);
        float z32 = blo(r2.x), z400 = bhi(r2.x);
        float z401 = blo(r2.y), z402 = bhi(r2.y);
        float z410 = blo(r3.x), z411 = bhi(r3.x);
        float z412 = blo(r3.y), z420 = bhi(r3.y);
        float z421 = blo(r4.x), z422 = bhi(r4.x);

        g0 = fmaf(y0, s, g0);
        g1x = fmaf(z10, s, g1x); g1y = fmaf(z11, s, g1y); g1z = fmaf(z12, s, g1z);
        g2x = fmaf(y0, vx, g2x); g2y = fmaf(y0, vy, g2y); g2z = fmaf(y0, vz, g2z);
        g3 = fmaf(z30, vx, fmaf(z31, vy, fmaf(z32, vz, g3)));
        g4x = fmaf(vx, z400, fmaf(vy, z410, fmaf(vz, z420, g4x)));
        g4y = fmaf(vx, z401, fmaf(vy, z411, fmaf(vz, z421, g4y)));
        g4z = fmaf(vx, z402, fmaf(vy, z412, fmaf(vz, z422, g4z)));
    }
    g0 += __shfl_xor(g0, 32);  g3 += __shfl_xor(g3, 32);
    g1x += __shfl_xor(g1x, 32); g1y += __shfl_xor(g1y, 32); g1z += __shfl_xor(g1z, 32);
    g2x += __shfl_xor(g2x, 32); g2y += __shfl_xor(g2y, 32); g2z += __shfl_xor(g2z, 32);
    g4x += __shfl_xor(g4x, 32); g4y += __shfl_xor(g4y, 32); g4z += __shfl_xor(g4z, 32);

    if (half == 0) {
        unsigned short* Gr = G + (size_t)wave * 352 + u;
        Gr[0] = bh(g0);         // t=0
        Gr[32] = bh(g3);        // t=1
        Gr[64] = bh(g1x);  Gr[96] = bh(g1y);  Gr[128] = bh(g1z);
        Gr[160] = bh(g2x); Gr[192] = bh(g2y); Gr[224] = bh(g2z);
        Gr[256] = bh(g4x); Gr[288] = bh(g4y); Gr[320] = bh(g4z);
    }
}

// ---------------------------------------------------------------------------
// Epilogue: out[n][j] = Sum_k G[n][k]*WBT[j][k] via mfma_f32_16x16x32_bf16.
// One wave per 16-dst tile; A-frags (K=352 -> 11) held in regs across the 8
// j-tiles. D: lane l reg i -> out[n0+(l>>4)*4+i][jt*16+(l&15)].
// ---------------------------------------------------------------------------
__global__ __launch_bounds__(256) void epilogue_kernel(
    const unsigned short* __restrict__ G, const unsigned short* __restrict__ WBT,
    float* __restrict__ out, int N) {
    int wid = (blockIdx.x * 256 + threadIdx.x) >> 6;
    int lane = threadIdx.x & 63;
    int ntiles = N >> 4;
    if (wid >= ntiles) return;
    int n0 = wid << 4;
    int r = lane & 15, q = lane >> 4;

    bf16x8 a[11];
#pragma unroll
    for (int kk = 0; kk < 11; ++kk)
        a[kk] = *(const bf16x8*)(G + (size_t)(n0 + r) * 352 + kk * 32 + q * 8);

#pragma unroll
    for (int jt = 0; jt < 8; ++jt) {
        f32x4 acc = {0.f, 0.f, 0.f, 0.f};
#pragma unroll
        for (int kk = 0; kk < 11; ++kk) {
            bf16x8 b = *(const bf16x8*)(WBT + (size_t)(jt * 16 + r) * 352 + kk * 32 + q * 8);
            acc = __builtin_amdgcn_mfma_f32_16x16x32_bf16(a[kk], b, acc, 0, 0, 0);
        }
#pragma unroll
        for (int i = 0; i < 4; ++i)
            out[(size_t)(n0 + q * 4 + i) * 128 + jt * 16 + r] = acc[i];
    }
}

extern "C" void kernel_launch(void* const* d_in, const int* in_sizes, int n_in,
                              void* d_out, int out_size, void* d_ws, size_t ws_size,
                              hipStream_t stream) {
    const float* feat = (const float*)d_in[0];
    const float* sh = (const float*)d_in[1];
    const int* eidx = (const int*)d_in[2];
    const float* W = (const float*)d_in[3];
    float* out = (float*)d_out;
    int N = in_sizes[0] / 128;
    int E = in_sizes[1] / 9;

    float* wsf = (float*)d_ws;
    float* cg = wsf;                                       // 128 words
    int* cursor = (int*)(wsf + 128);                       // N words
    size_t off = (size_t)(128 + N + 1) & ~(size_t)1;       // 8B align
    unsigned* zrec = (unsigned*)(wsf + off);               // 10E words
    unsigned* fb = zrec + (size_t)10 * E;                  // 64N words
    unsigned short* G = (unsigned short*)(fb + (size_t)64 * N);  // 176N words
    unsigned short* WBT = G + (size_t)352 * N;             // 22528 words (ushort)
    int* tilesums = (int*)(WBT + 45056);                   // 256 words

    int tiles = (N + 255) / 256;

    hipMemsetAsync(cursor, 0, (size_t)N * sizeof(int), stream);
    prep_kernel<<<(N * 32 + 255) / 256, 256, 0, stream>>>(feat, eidx, cursor, fb, cg, N, E);
    scanA_kernel<<<tiles, 256, 0, stream>>>(cursor, tilesums, N, W, cg, WBT);
    scanB_kernel<<<1, 256, 0, stream>>>(tilesums, tiles);
    scanC_kernel<<<tiles, 256, 0, stream>>>(cursor, tilesums, N);
    zscatter_kernel<<<(E + 255) / 256, 256, 0, stream>>>(eidx, sh, cg, cursor, zrec, E);
    gather_kernel<<<(N * 64 + 255) / 256, 256, 0, stream>>>(fb, zrec, cursor, G, N);
    epilogue_kernel<<<((N >> 4) * 64 + 255) / 256, 256, 0, stream>>>(G, WBT, out, N);
}

// Round 11
// 179.479 us; speedup vs baseline: 1.8681x; 1.0361x over previous
//
#include <hip/hip_runtime.h>
#include <math.h>

// ---------------------------------------------------------------------------
// u-space aggregation + fused MFMA epilogue.
//   gather:  G[n][t][u] = Sum_{e->n} z_t(Y_e) (x) feat_u[src_e]  (LDS, bf16)
//   fused:   out[n][j]  = Sum_k G[n][k] * WBT[j][k]  (16x16x32 bf16 MFMA)
// Workspace (4B words):
//   cg      [0..128)        CG tensors (alpha/norm folded)
//   cursor  [128 .. +N)     memset0 -> hist -> prefix -> cursor -> row ends
//   zrec    [.. +10E)       dst-sorted 40B records (8B aligned)
//   fb      [.. +64N)       feat bf16 [N][32] uint2 {P(s,vx),P(vy,vz)}
//   WBT     [.. +22528)     ushort [128][352]  (W bf16, cg0/c2 folded)
//   tilesums[.. +256)       per-tile sums for hierarchical scan
// ---------------------------------------------------------------------------

typedef __attribute__((ext_vector_type(8))) short bf16x8;
typedef __attribute__((ext_vector_type(4))) float f32x4;

__device__ inline float blo(unsigned u) { return __uint_as_float(u << 16); }
__device__ inline float bhi(unsigned u) { return __uint_as_float(u & 0xffff0000u); }
__device__ inline unsigned bpack(float a, float b) {
    unsigned ua = __float_as_uint(a);
    ua = (ua + 0x7fffu + ((ua >> 16) & 1u)) >> 16;
    unsigned ub = __float_as_uint(b);
    ub = (ub + 0x7fffu + ((ub >> 16) & 1u)) & 0xffff0000u;
    return ua | ub;
}
__device__ inline unsigned short bh(float a) {
    unsigned ua = __float_as_uint(a);
    return (unsigned short)((ua + 0x7fffu + ((ua >> 16) & 1u)) >> 16);
}

// f32 factorial (all n <= 7 here; exact in f32). Register-only scalar loop.
__device__ inline float dfactf(int n) {
    float r = 1.0f;
    for (int i = 2; i <= n; ++i) r *= (float)i;
    return r;
}

// SU(2) "CG" element via the reference's exact Racah-form (all six m-dependent
// factorials in the NUMERATOR — non-standard but matches the reference).
__device__ float su2_cg_elem_f(int l1, int l2, int l3, int i, int k, int n) {
    int m1 = i - l1, m2 = k - l2, m3 = n - l3;
    if (m1 + m2 != m3) return 0.0f;
    int vmin = -l1 + l2 + m3;
    if (-l1 + m1 > vmin) vmin = -l1 + m1;
    if (0 > vmin) vmin = 0;
    int vmax = l2 + l3 + m1;
    if (l3 - l1 + l2 < vmax) vmax = l3 - l1 + l2;
    if (l3 + m3 < vmax) vmax = l3 + m3;
    if (vmax < vmin) return 0.0f;
    float c = sqrtf((float)(2 * l3 + 1) * dfactf(l3 + l1 - l2) *
                    dfactf(l3 - l1 + l2) * dfactf(l1 + l2 - l3) /
                    dfactf(l1 + l2 + l3 + 1));
    c *= sqrtf(dfactf(l3 + m3) * dfactf(l3 - m3) * dfactf(l1 - m1) *
               dfactf(l1 + m1) * dfactf(l2 - m2) * dfactf(l2 + m2));
    float s = 0.0f;
    for (int v = vmin; v <= vmax; ++v) {
        float term = dfactf(l2 + l3 + m1 - v) * dfactf(l1 - m1 + v) /
                     (dfactf(v) * dfactf(l3 - l1 + l2 - v) *
                      dfactf(l3 + m3 - v) * dfactf(v + l1 - l2 - m3));
        if ((v + l2 + m2) & 1) term = -term;
        s += term;
    }
    return c * s;
}

// cg compute by one 256-thread block. All dynamically-indexed arrays in LDS
// (runtime-indexed private arrays go to SCRATCH -> 110us straggler, rule #20).
__device__ void cg_compute_block(float* __restrict__ cg_out) {
    __shared__ float sqr[3][5][5], sqi[3][5][5];  // q matrices for l=0,1,2
    __shared__ float vals[5][45];
    int t = threadIdx.x;
    if (t < 75) {
        int l = t / 25, a = (t % 25) / 5, b = t % 5;
        float re = 0.f, im = 0.f;
        const float inv = 0.70710678118654752440f;
        int m = a - l;
        if (a < 5 && b < 5) {
            if (m < 0) {
                if (b == l - m) re = inv;        // col l+|m|
                if (b == l + m) im = -inv;       // col l-|m|
            } else if (m == 0) {
                if (b == l && a == l) re = 1.f;
            } else {
                float sgn = (m & 1) ? -1.f : 1.f;
                if (b == l + m) re = sgn * inv;
                if (b == l - m) im = sgn * inv;
            }
        }
        if (l == 1) { float r = re; re = im; im = -r; }      // * (-i)
        else if (l == 2) { re = -re; im = -im; }             // * (-1)
        sqr[l][a][b] = re;
        sqi[l][a][b] = im;
    }
    __syncthreads();
    const int l1s[5] = {0, 0, 1, 1, 1};
    const int l2s[5] = {0, 1, 0, 1, 2};
    const int l3s[5] = {0, 1, 1, 0, 1};
    const int offs[5] = {0, 1, 10, 19, 28};
    const float alphas[5] = {0.125f, 0.10206207261596575f, 0.10206207261596575f,
                             0.125f, 0.10206207261596575f};
    int p = t / 45, idx = t % 45;
    bool active = (t < 225);
    float acc = 0.0f;
    int d1 = 0, d2 = 0, d3 = 0;
    if (active) {
        int l1 = l1s[p], l2 = l2s[p], l3 = l3s[p];
        d1 = 2 * l1 + 1; d2 = 2 * l2 + 1; d3 = 2 * l3 + 1;
        if (idx < d1 * d2 * d3) {
            int j = idx / (d2 * d3);
            int rem = idx % (d2 * d3);
            int l_ = rem / d3, m = rem % d3;
            for (int i = 0; i < d1; ++i)
                for (int k = 0; k < d2; ++k)
                    for (int n = 0; n < d3; ++n) {
                        float C = su2_cg_elem_f(l1, l2, l3, i, k, n);
                        if (C == 0.0f) continue;
                        float ar = sqr[l1][i][j], ai = sqi[l1][i][j];
                        float br = sqr[l2][k][l_], bi = sqi[l2][k][l_];
                        float cr = sqr[l3][n][m], ci = sqi[l3][n][m];
                        float abr = ar * br - ai * bi;
                        float abi = ar * bi + ai * br;
                        acc += (abr * cr + abi * ci) * C;  // Re(a*b*conj(c))
                    }
        }
        vals[p][idx] = acc;
    }
    __syncthreads();
    if (active && idx < d1 * d2 * d3) {
        float n2 = 0.0f;
        for (int q = 0; q < 45; ++q) n2 += vals[p][q] * vals[p][q];
        cg_out[offs[p] + idx] = acc * alphas[p] / sqrtf(n2);
    }
}

// ---------------------------------------------------------------------------
// prep: cg (block 0, LDS-based) + feat->bf16 transcode + dst histogram
// ---------------------------------------------------------------------------
__global__ __launch_bounds__(256) void prep_kernel(
    const float* __restrict__ feat, const int* __restrict__ eidx,
    int* __restrict__ cursor, unsigned* __restrict__ fb,
    float* __restrict__ cg, int N, int E) {
    if (blockIdx.x == 0) cg_compute_block(cg);
    int t = blockIdx.x * 256 + threadIdx.x;
    if (t < N * 32) {
        int n = t >> 5, u = t & 31;
        const float* f = feat + (size_t)n * 128;
        float s = f[u];
        float vx = f[32 + 3 * u], vy = f[33 + 3 * u], vz = f[34 + 3 * u];
        ((uint2*)fb)[t] = make_uint2(bpack(s, vx), bpack(vy, vz));
    }
    if (t < E) atomicAdd(&cursor[eidx[E + t]], 1);
}

// ---------------------------------------------------------------------------
// scanA (fused with WBT build)
// WBT[j][k], k = t*32+u:  j<32 (out0): t0 -> cg0*w0, t1 -> w3
//   j>=32: w=(j-32)/3, m=(j-32)%3: t2+mm -> (mm==m)*w1 ;
//   t5+i -> c2[i][m]*w2 ; t8+mm -> (mm==m)*w4
// ---------------------------------------------------------------------------
__global__ __launch_bounds__(256) void scanA_kernel(
    const int* __restrict__ counts, int* __restrict__ tilesums, int N,
    const float* __restrict__ W, const float* __restrict__ cg,
    unsigned short* __restrict__ WBT) {
    __shared__ int lds[4];
    int i = blockIdx.x * 256 + threadIdx.x;
    int v = (i < N) ? counts[i] : 0;
#pragma unroll
    for (int d = 1; d < 64; d <<= 1) v += __shfl_xor(v, d);
    int wid = threadIdx.x >> 6;
    if ((threadIdx.x & 63) == 0) lds[wid] = v;
    __syncthreads();
    if (threadIdx.x == 0)
        tilesums[blockIdx.x] = lds[0] + lds[1] + lds[2] + lds[3];
    int idx = i;
    if (idx < 128 * 352) {
        int j = idx / 352, k = idx % 352;
        int t = k >> 5, u = k & 31;
        float val = 0.f;
        if (j < 32) {
            if (t == 0) val = cg[0] * W[u * 32 + j];
            else if (t == 1) val = W[3072 + u * 32 + j];
        } else {
            int w = (j - 32) / 3, m = (j - 32) % 3;
            if (t >= 2 && t <= 4) { if (t - 2 == m) val = W[1024 + u * 32 + w]; }
            else if (t >= 5 && t <= 7) { val = cg[10 + (t - 5) * 3 + m] * W[2048 + u * 32 + w]; }
            else if (t >= 8) { if (t - 8 == m) val = W[4096 + u * 32 + w]; }
        }
        WBT[idx] = bh(val);
    }
}

__global__ __launch_bounds__(256) void scanB_kernel(
    int* __restrict__ tilesums, int tiles) {
    __shared__ int lds[4];
    int tid = threadIdx.x;
    int v = (tid < tiles) ? tilesums[tid] : 0;
    int orig = v;
#pragma unroll
    for (int d = 1; d < 64; d <<= 1) {
        int t = __shfl_up(v, d);
        if ((tid & 63) >= d) v += t;
    }
    int wid = tid >> 6;
    if ((tid & 63) == 63) lds[wid] = v;
    __syncthreads();
    int base = 0;
    for (int q = 0; q < wid; ++q) base += lds[q];
    if (tid < tiles) tilesums[tid] = base + v - orig;  // exclusive
}

__global__ __launch_bounds__(256) void scanC_kernel(
    int* __restrict__ counts, const int* __restrict__ tilesums, int N) {
    __shared__ int lds[4];
    int i = blockIdx.x * 256 + threadIdx.x;
    int tid = threadIdx.x;
    int v = (i < N) ? counts[i] : 0;
    int orig = v;
#pragma unroll
    for (int d = 1; d < 64; d <<= 1) {
        int t = __shfl_up(v, d);
        if ((tid & 63) >= d) v += t;
    }
    int wid = tid >> 6;
    if ((tid & 63) == 63) lds[wid] = v;
    __syncthreads();
    int base = tilesums[blockIdx.x];
    for (int q = 0; q < wid; ++q) base += lds[q];
    if (i < N) counts[i] = base + v - orig;  // exclusive prefix
}

// ---------------------------------------------------------------------------
// zscatter: per edge compute 16 lane-invariant values (CG (x) Y folded),
// write one 40B (8B-aligned) record at the dst-sorted position.
// ---------------------------------------------------------------------------
__global__ __launch_bounds__(256) void zscatter_kernel(
    const int* __restrict__ eidx, const float* __restrict__ sh,
    const float* __restrict__ cg, int* __restrict__ cursor,
    unsigned* __restrict__ zrec, int E) {
    int t = blockIdx.x * 256 + threadIdx.x;
    if (t >= E) return;
    int src = eidx[t];
    int dst = eidx[E + t];
    int pos = atomicAdd(&cursor[dst], 1);
    const float* Ye = sh + (size_t)t * 9;
    float Y0 = Ye[0];
    float Y1v[3] = {Ye[1], Ye[2], Ye[3]};
    float Y2v[5] = {Ye[4], Ye[5], Ye[6], Ye[7], Ye[8]};
    float Z1[3], Z3[3], Z4[9];
#pragma unroll
    for (int m = 0; m < 3; ++m)
        Z1[m] = fmaf(Y1v[0], cg[1 + m],
                fmaf(Y1v[1], cg[4 + m], Y1v[2] * cg[7 + m]));
#pragma unroll
    for (int i = 0; i < 3; ++i)
        Z3[i] = fmaf(Y1v[0], cg[19 + i * 3],
                fmaf(Y1v[1], cg[19 + i * 3 + 1], Y1v[2] * cg[19 + i * 3 + 2]));
#pragma unroll
    for (int i = 0; i < 3; ++i)
#pragma unroll
        for (int m = 0; m < 3; ++m) {
            float acc = 0.f;
#pragma unroll
            for (int j = 0; j < 5; ++j)
                acc = fmaf(Y2v[j], cg[28 + (i * 5 + j) * 3 + m], acc);
            Z4[i * 3 + m] = acc;
        }
    uint2* rec = (uint2*)(zrec + (size_t)pos * 10);
    rec[0] = make_uint2((unsigned)src, bpack(Y0, Z1[0]));
    rec[1] = make_uint2(bpack(Z1[1], Z1[2]), bpack(Z3[0], Z3[1]));
    rec[2] = make_uint2(bpack(Z3[2], Z4[0]), bpack(Z4[1], Z4[2]));
    rec[3] = make_uint2(bpack(Z4[3], Z4[4]), bpack(Z4[5], Z4[6]));
    rec[4] = make_uint2(bpack(Z4[7], Z4[8]), 0u);
}
// After zscatter: cursor[d] == end of d's range.

// ---------------------------------------------------------------------------
// Fused gather + MFMA: one block per 16-dst tile. Phase 1: wave wv gathers
// dsts base+wv*4..+3 (one wave per dst at a time; lane u=lane&31, halves take
// alternate edges, shfl_xor(32) combine) and writes bf16 g-values to LDS
// Gs[16][360] (720B row stride; frag reads 16B aligned). Phase 2 (after
// barrier): each wave computes 2 j-tiles of out[n][j] = Sum_k G[n][k]WBT[j][k]
// via mfma_f32_16x16x32_bf16 (A from LDS, B from L2-resident WBT).
// D layout: lane l reg i -> out[base+(l>>4)*4+i][jt*16+(l&15)]  (verified).
// ---------------------------------------------------------------------------
__global__ __launch_bounds__(256) void gather_mfma_kernel(
    const unsigned* __restrict__ fb, const unsigned* __restrict__ zrec,
    const int* __restrict__ cursor, const unsigned short* __restrict__ WBT,
    float* __restrict__ out, int N) {
    __shared__ unsigned short Gs[16][360];
    int wv = threadIdx.x >> 6;
    int lane = threadIdx.x & 63;
    int half = lane >> 5, u = lane & 31;
    int base = blockIdx.x << 4;

#pragma unroll 1
    for (int d = 0; d < 4; ++d) {
        int row = wv * 4 + d;
        int node = base + row;
        if (node >= N) break;
        int start = node ? cursor[node - 1] : 0;
        int end = cursor[node];

        float g0 = 0.f, g3 = 0.f;
        float g1x = 0.f, g1y = 0.f, g1z = 0.f;
        float g2x = 0.f, g2y = 0.f, g2z = 0.f;
        float g4x = 0.f, g4y = 0.f, g4z = 0.f;

        for (int idx = start + half; idx < end; idx += 2) {
            const uint2* r = (const uint2*)(zrec + (size_t)idx * 10);
            uint2 r0 = r[0], r1 = r[1], r2 = r[2], r3 = r[3], r4 = r[4];
            int src = (int)r0.x;
            uint2 f2 = ((const uint2*)fb)[(size_t)src * 32 + u];
            float s = blo(f2.x), vx = bhi(f2.x);
            float vy = blo(f2.y), vz = bhi(f2.y);
            float y0 = blo(r0.y), z10 = bhi(r0.y);
            float z11 = blo(r1.x), z12 = bhi(r1.x);
            float z30 = blo(r1.y), z31 = bhi(r1.y);
            float z32 = blo(r2.x), z400 = bhi(r2.x);
            float z401 = blo(r2.y), z402 = bhi(r2.y);
            float z410 = blo(r3.x), z411 = bhi(r3.x);
            float z412 = blo(r3.y), z420 = bhi(r3.y);
            float z421 = blo(r4.x), z422 = bhi(r4.x);

            g0 = fmaf(y0, s, g0);
            g1x = fmaf(z10, s, g1x); g1y = fmaf(z11, s, g1y); g1z = fmaf(z12, s, g1z);
            g2x = fmaf(y0, vx, g2x); g2y = fmaf(y0, vy, g2y); g2z = fmaf(y0, vz, g2z);
            g3 = fmaf(z30, vx, fmaf(z31, vy, fmaf(z32, vz, g3)));
            g4x = fmaf(vx, z400, fmaf(vy, z410, fmaf(vz, z420, g4x)));
            g4y = fmaf(vx, z401, fmaf(vy, z411, fmaf(vz, z421, g4y)));
            g4z = fmaf(vx, z402, fmaf(vy, z412, fmaf(vz, z422, g4z)));
        }
        g0 += __shfl_xor(g0, 32);  g3 += __shfl_xor(g3, 32);
        g1x += __shfl_xor(g1x, 32); g1y += __shfl_xor(g1y, 32); g1z += __shfl_xor(g1z, 32);
        g2x += __shfl_xor(g2x, 32); g2y += __shfl_xor(g2y, 32); g2z += __shfl_xor(g2z, 32);
        g4x += __shfl_xor(g4x, 32); g4y += __shfl_xor(g4y, 32); g4z += __shfl_xor(g4z, 32);

        if (half == 0) {
            unsigned short* Gr = &Gs[row][u];
            Gr[0] = bh(g0);         // t=0
            Gr[32] = bh(g3);        // t=1
            Gr[64] = bh(g1x);  Gr[96] = bh(g1y);  Gr[128] = bh(g1z);
            Gr[160] = bh(g2x); Gr[192] = bh(g2y); Gr[224] = bh(g2z);
            Gr[256] = bh(g4x); Gr[288] = bh(g4y); Gr[320] = bh(g4z);
        }
    }
    __syncthreads();

    int r = lane & 15, q = lane >> 4;
    bf16x8 a[11];
#pragma unroll
    for (int kk = 0; kk < 11; ++kk)
        a[kk] = *(const bf16x8*)(&Gs[r][kk * 32 + q * 8]);

#pragma unroll
    for (int jj = 0; jj < 2; ++jj) {
        int jt = wv * 2 + jj;
        f32x4 acc = {0.f, 0.f, 0.f, 0.f};
#pragma unroll
        for (int kk = 0; kk < 11; ++kk) {
            bf16x8 b = *(const bf16x8*)(WBT + (size_t)(jt * 16 + r) * 352 + kk * 32 + q * 8);
            acc = __builtin_amdgcn_mfma_f32_16x16x32_bf16(a[kk], b, acc, 0, 0, 0);
        }
#pragma unroll
        for (int i = 0; i < 4; ++i) {
            int n = base + q * 4 + i;
            if (n < N) out[(size_t)n * 128 + jt * 16 + r] = acc[i];
        }
    }
}

extern "C" void kernel_launch(void* const* d_in, const int* in_sizes, int n_in,
                              void* d_out, int out_size, void* d_ws, size_t ws_size,
                              hipStream_t stream) {
    const float* feat = (const float*)d_in[0];
    const float* sh = (const float*)d_in[1];
    const int* eidx = (const int*)d_in[2];
    const float* W = (const float*)d_in[3];
    float* out = (float*)d_out;
    int N = in_sizes[0] / 128;
    int E = in_sizes[1] / 9;

    float* wsf = (float*)d_ws;
    float* cg = wsf;                                       // 128 words
    int* cursor = (int*)(wsf + 128);                       // N words
    size_t off = (size_t)(128 + N + 1) & ~(size_t)1;       // 8B align
    unsigned* zrec = (unsigned*)(wsf + off);               // 10E words
    unsigned* fb = zrec + (size_t)10 * E;                  // 64N words
    unsigned short* WBT = (unsigned short*)(fb + (size_t)64 * N);  // 22528 words
    int* tilesums = (int*)(WBT + 45056);                   // 256 words

    int tiles = (N + 255) / 256;
    int ntiles16 = (N + 15) / 16;

    hipMemsetAsync(cursor, 0, (size_t)N * sizeof(int), stream);
    prep_kernel<<<(N * 32 + 255) / 256, 256, 0, stream>>>(feat, eidx, cursor, fb, cg, N, E);
    scanA_kernel<<<tiles, 256, 0, stream>>>(cursor, tilesums, N, W, cg, WBT);
    scanB_kernel<<<1, 256, 0, stream>>>(tilesums, tiles);
    scanC_kernel<<<tiles, 256, 0, stream>>>(cursor, tilesums, N);
    zscatter_kernel<<<(E + 255) / 256, 256, 0, stream>>>(eidx, sh, cg, cursor, zrec, E);
    gather_mfma_kernel<<<ntiles16, 256, 0, stream>>>(fb, zrec, cursor, WBT, out, N);
}